// Round 7
// baseline (425.683 us; speedup 1.0000x reference)
//
#include <hip/hip_runtime.h>
#include <math.h>

#define TT 2048
#define DD 256
#define NBATCH 8
#define EPSF 1e-8f

typedef unsigned short u16;
typedef __attribute__((ext_vector_type(8))) short short8;
typedef __attribute__((ext_vector_type(4))) float f32x4;

__device__ __forceinline__ u16 f2bf(float x) {
    unsigned int u = __builtin_bit_cast(unsigned int, x);
    u += 0x7fffu + ((u >> 16) & 1u);
    return (u16)(u >> 16);
}
__device__ __forceinline__ float bf2f(u16 h) {
    return __builtin_bit_cast(float, (unsigned int)h << 16);
}

// MFMA-fragment LDS index for a [rows x 32k] bf16 tile:
// elem(row,k) -> (((row>>4)*4+(k>>3))*16+(row&15))*8+(k&7)
// Fragment read for 16-row subtile t is ds_read_b128 at (t*64+lane)*8.
__device__ __forceinline__ int frag_dst(int row, int k) {
    return (((row >> 4) * 4 + (k >> 3)) * 16 + (row & 15)) * 8 + (k & 7);
}

// Address-pure bank swizzle (u16 index), applied to both write and read.
__device__ __forceinline__ int swz(int i) { return i ^ ((i >> 2) & 32); }

template<int BR>
__device__ __forceinline__ void stage_tile(const u16* __restrict__ g, u16* s,
                                           int row0, int k0, int ldk, int tid)
{
    #pragma unroll
    for (int i = 0; i < BR / 64; ++i) {
        const int c = tid + 256 * i;
        const int row = c >> 2, q = c & 3;
        *(int4*)(s + swz(frag_dst(row, q * 8))) =
            *(const int4*)(g + (long)(row0 + row) * ldk + k0 + q * 8);
    }
}

// ---------------------------------------------------------------------------
// Combined projections. z = 0:v2(split h/l) 1:a1(split h/l)
//                        2:v1 -> v1T (register-transposed bf16)
//                        3:a2 -> a2T
// 3-term split-bf16 MFMA (rel err ~3e-6). 512 threads = 8 waves (2 wy x
// 4 wx), BM=128, BN=64. Outputs bit-identical to the 256-thread version.
// ---------------------------------------------------------------------------
__global__ __launch_bounds__(512)
void proj_kernel(const u16* __restrict__ vfh, const u16* __restrict__ vfl,
                 const u16* __restrict__ afh, const u16* __restrict__ afl,
                 const u16* __restrict__ Wsp,
                 u16* __restrict__ v2h, u16* __restrict__ v2l,
                 u16* __restrict__ a1h, u16* __restrict__ a1l,
                 u16* __restrict__ v1T, u16* __restrict__ a2T)
{
    const int zz = blockIdx.z;
    const u16* Ah = (zz == 1 || zz == 3) ? afh : vfh;
    const u16* Al = (zz == 1 || zz == 3) ? afl : vfl;
    const int widx = (zz == 0) ? 2 : (zz == 1) ? 4 : (zz == 2) ? 0 : 6;
    const u16* Bh = Wsp + widx * DD * DD;
    const u16* Bl = Bh + DD * DD;
    const bool split = zz < 2;
    u16* Oh = (zz == 0) ? v2h : a1h;
    u16* Ol = (zz == 0) ? v2l : a1l;
    u16* OT = (zz == 2) ? v1T : a2T;

    __shared__ __align__(16) u16 Ah_s[128 * 32], Al_s[128 * 32];
    __shared__ __align__(16) u16 Bh_s[64 * 32], Bl_s[64 * 32];
    const int m0 = blockIdx.y * 128, n0 = blockIdx.x * 64;
    const int tid = threadIdx.x, lane = tid & 63, w = tid >> 6;
    const int wy = w >> 2, wx = w & 3;
    f32x4 acc[4] = {};

    // A staging: all 512 threads, 1 chunk per tile (row tid>>2, q tid&3)
    const int prow = tid >> 2, pq = tid & 3;
    const int dA = swz(frag_dst(prow, pq * 8));
    const u16* gAh = Ah + (long)(m0 + prow) * DD + pq * 8;
    const u16* gAl = Al + (long)(m0 + prow) * DD + pq * 8;
    // B staging: tid<256 -> Bh, tid>=256 -> Bl (row (tid&255)>>2)
    const int brow = (tid & 255) >> 2, bq = tid & 3;
    const int dB = swz(frag_dst(brow, bq * 8));
    const u16* gB = ((tid < 256) ? Bh : Bl) + (long)(n0 + brow) * DD + bq * 8;
    u16* sB = (tid < 256) ? Bh_s : Bl_s;

    int4 rAh = *(const int4*)(gAh);
    int4 rAl = *(const int4*)(gAl);
    int4 rB  = *(const int4*)(gB);

    for (int k0 = 0; k0 < DD; k0 += 32) {
        *(int4*)(Ah_s + dA) = rAh;
        *(int4*)(Al_s + dA) = rAl;
        *(int4*)(sB + dB)   = rB;
        __syncthreads();
        const int kn = (k0 + 32 < DD) ? k0 + 32 : 0;
        rAh = *(const int4*)(gAh + kn);
        rAl = *(const int4*)(gAl + kn);
        rB  = *(const int4*)(gB + kn);
        short8 ah[4], al[4], bh, bl;
        #pragma unroll
        for (int i = 0; i < 4; ++i) {
            ah[i] = *(const short8*)(Ah_s + swz(((wy * 4 + i) * 64 + lane) * 8));
            al[i] = *(const short8*)(Al_s + swz(((wy * 4 + i) * 64 + lane) * 8));
        }
        bh = *(const short8*)(Bh_s + swz((wx * 64 + lane) * 8));
        bl = *(const short8*)(Bl_s + swz((wx * 64 + lane) * 8));
        #pragma unroll
        for (int i = 0; i < 4; ++i) {
            acc[i] = __builtin_amdgcn_mfma_f32_16x16x32_bf16(ah[i], bl, acc[i], 0, 0, 0);
            acc[i] = __builtin_amdgcn_mfma_f32_16x16x32_bf16(al[i], bh, acc[i], 0, 0, 0);
            acc[i] = __builtin_amdgcn_mfma_f32_16x16x32_bf16(ah[i], bh, acc[i], 0, 0, 0);
        }
        __syncthreads();
    }
    const int quad = lane >> 4, col = lane & 15;
    const int c = n0 + wx * 16 + col;
    #pragma unroll
    for (int i = 0; i < 4; ++i) {
        const int rbase = m0 + wy * 64 + i * 16 + quad * 4;
        if (split) {
            #pragma unroll
            for (int r = 0; r < 4; ++r) {
                const float v = fmaxf(acc[i][r], 0.f);
                const u16 h = f2bf(v);
                Oh[(long)(rbase + r) * DD + c] = h;
                Ol[(long)(rbase + r) * DD + c] = f2bf(v - bf2f(h));
            }
        } else {
            // transposed: OT[b][d=c][t]; 4 consecutive t = one b64 store
            short4 pk;
            pk.x = (short)f2bf(fmaxf(acc[i][0], 0.f));
            pk.y = (short)f2bf(fmaxf(acc[i][1], 0.f));
            pk.z = (short)f2bf(fmaxf(acc[i][2], 0.f));
            pk.w = (short)f2bf(fmaxf(acc[i][3], 0.f));
            const int b = rbase >> 11, t = rbase & (TT - 1);
            *(short4*)(OT + ((long)b * DD + c) * TT + t) = pk;
        }
    }
}

// ---------------------------------------------------------------------------
// Scores: beta(bf16) = relu(v2.a1/16), 3-term split MFMA. BM=BN=128.
// 512 threads = 8 waves (2 wy x 4 wx), verified R5 pipeline.
// XCD-affine remap (T1, bijective: 2048 blocks = 8 XCDs x 256 tiles):
// flat%8 = batch z -> all tiles of batch z land on XCD z (HW dispatches
// flat id round-robin over 8 XCDs). Per-XCD L2 working set drops from
// 33.6 MB (all batches' v2/a1) to 8.4 MB (one batch).
// ---------------------------------------------------------------------------
__global__ __launch_bounds__(512)
void score_kernel(const u16* __restrict__ v2h, const u16* __restrict__ v2l,
                  const u16* __restrict__ a1h, const u16* __restrict__ a1l,
                  u16* __restrict__ beta, u16* __restrict__ betaT,
                  float* __restrict__ rs, float* __restrict__ cs)
{
    // S serves as: 4 staging tiles (32 KB) in the K-loop, then the 128x128
    // store buffer (stride 136, 34 KB) in the epilogue.
    __shared__ __align__(16) u16 S[128 * 136];
    u16* Ah_s = S;
    u16* Al_s = S + 4096;
    u16* Bh_s = S + 8192;
    u16* Bl_s = S + 12288;
    // XCD-affine decode: flat = x + 16y + 256z_raw; z = flat&7, tile = flat>>3
    const int flat = blockIdx.x + (blockIdx.y << 4) + (blockIdx.z << 8);
    const int z = flat & 7;
    const int tile = flat >> 3;                      // 0..255
    const int m0 = (tile >> 4) * 128, n0 = (tile & 15) * 128;
    const int tid = threadIdx.x, lane = tid & 63, w = tid >> 6;
    const int wy = w >> 2, wx = w & 3;              // 2 x 4 waves
    const long zoff = (long)z * TT * DD;
    f32x4 acc[4][2] = {};

    // staging: 512 threads, one 16B chunk per tile per thread
    const int prow = tid >> 2, pq = tid & 3;        // row 0..127, k-chunk 0..3
    const int d0 = swz(frag_dst(prow, pq * 8));
    const u16* gAh = v2h + zoff + (long)(m0 + prow) * DD + pq * 8;
    const u16* gAl = v2l + zoff + (long)(m0 + prow) * DD + pq * 8;
    const u16* gBh = a1h + zoff + (long)(n0 + prow) * DD + pq * 8;
    const u16* gBl = a1l + zoff + (long)(n0 + prow) * DD + pq * 8;

    int4 rAh = *(const int4*)(gAh);
    int4 rAl = *(const int4*)(gAl);
    int4 rBh = *(const int4*)(gBh);
    int4 rBl = *(const int4*)(gBl);

    for (int k0 = 0; k0 < DD; k0 += 32) {
        *(int4*)(Ah_s + d0) = rAh;
        *(int4*)(Al_s + d0) = rAl;
        *(int4*)(Bh_s + d0) = rBh;
        *(int4*)(Bl_s + d0) = rBl;
        __syncthreads();
        // prefetch k0+32 (last iter: harmless reload of k=0)
        const int kn = (k0 + 32 < DD) ? k0 + 32 : 0;
        rAh = *(const int4*)(gAh + kn);
        rAl = *(const int4*)(gAl + kn);
        rBh = *(const int4*)(gBh + kn);
        rBl = *(const int4*)(gBl + kn);
        short8 ah[4], al[4], bh[2], bl[2];
        #pragma unroll
        for (int i = 0; i < 4; ++i) {
            ah[i] = *(const short8*)(Ah_s + swz(((wy * 4 + i) * 64 + lane) * 8));
            al[i] = *(const short8*)(Al_s + swz(((wy * 4 + i) * 64 + lane) * 8));
        }
        #pragma unroll
        for (int j = 0; j < 2; ++j) {
            bh[j] = *(const short8*)(Bh_s + swz(((wx * 2 + j) * 64 + lane) * 8));
            bl[j] = *(const short8*)(Bl_s + swz(((wx * 2 + j) * 64 + lane) * 8));
        }
        #pragma unroll
        for (int i = 0; i < 4; ++i)
            #pragma unroll
            for (int j = 0; j < 2; ++j) {
                acc[i][j] = __builtin_amdgcn_mfma_f32_16x16x32_bf16(ah[i], bl[j], acc[i][j], 0, 0, 0);
                acc[i][j] = __builtin_amdgcn_mfma_f32_16x16x32_bf16(al[i], bh[j], acc[i][j], 0, 0, 0);
                acc[i][j] = __builtin_amdgcn_mfma_f32_16x16x32_bf16(ah[i], bh[j], acc[i][j], 0, 0, 0);
            }
        __syncthreads();
    }

    const int quad = lane >> 4, col = lane & 15;
    const float scale = 1.f / 16.f;
    #pragma unroll
    for (int i = 0; i < 4; ++i)
        #pragma unroll
        for (int j = 0; j < 2; ++j)
            #pragma unroll
            for (int r = 0; r < 4; ++r)
                acc[i][j][r] = fmaxf(acc[i][j][r] * scale, 0.f);

    // beta row-major: stage into S[rl][cl] (stride 136), coalesced int4 out
    #pragma unroll
    for (int i = 0; i < 4; ++i) {
        const int rl = (wy * 4 + i) * 16 + quad * 4;
        #pragma unroll
        for (int j = 0; j < 2; ++j) {
            const int cl = (wx * 2 + j) * 16 + col;
            #pragma unroll
            for (int r = 0; r < 4; ++r)
                S[(rl + r) * 136 + cl] = f2bf(acc[i][j][r]);
        }
    }
    __syncthreads();
    #pragma unroll
    for (int it = 0; it < 4; ++it) {
        const int idx = tid + 512 * it;
        const int rl = idx >> 4, cq = idx & 15;
        const int4 v = *(const int4*)(S + rl * 136 + cq * 8);
        *(int4*)(beta + ((long)z * TT + m0 + rl) * TT + n0 + cq * 8) = v;
    }
    // row sums (fp32-exact atomics): wave partial = its 32 cols
    #pragma unroll
    for (int i = 0; i < 4; ++i)
        #pragma unroll
        for (int r = 0; r < 4; ++r) {
            float rp = acc[i][0][r] + acc[i][1][r];
            rp += __shfl_xor(rp, 1); rp += __shfl_xor(rp, 2);
            rp += __shfl_xor(rp, 4); rp += __shfl_xor(rp, 8);
            if (col == 0) {
                const int row = m0 + (wy * 4 + i) * 16 + quad * 4 + r;
                atomicAdd(&rs[(long)z * TT + row], rp);
            }
        }
    // col sums: wave partial = its 64 rows
    #pragma unroll
    for (int j = 0; j < 2; ++j) {
        float cp = 0.f;
        #pragma unroll
        for (int i = 0; i < 4; ++i)
            #pragma unroll
            for (int r = 0; r < 4; ++r) cp += acc[i][j][r];
        cp += __shfl_xor(cp, 16); cp += __shfl_xor(cp, 32);
        if (lane < 16) {
            const int c = n0 + (wx * 2 + j) * 16 + col;
            atomicAdd(&cs[(long)z * TT + c], cp);
        }
    }
    // betaT via LDS transpose: S[cl][rl] (stride 136), coalesced int4 out
    __syncthreads();
    #pragma unroll
    for (int i = 0; i < 4; ++i)
        #pragma unroll
        for (int j = 0; j < 2; ++j) {
            const int cl = (wx * 2 + j) * 16 + col;
            const int rl = (wy * 4 + i) * 16 + quad * 4;
            short4 pk;
            pk.x = (short)f2bf(acc[i][j][0]);
            pk.y = (short)f2bf(acc[i][j][1]);
            pk.z = (short)f2bf(acc[i][j][2]);
            pk.w = (short)f2bf(acc[i][j][3]);
            *(short4*)(S + cl * 136 + rl) = pk;
        }
    __syncthreads();
    #pragma unroll
    for (int it = 0; it < 4; ++it) {
        const int idx = tid + 512 * it;
        const int cl = idx >> 4, tq = idx & 15;
        const int4 v = *(const int4*)(S + cl * 136 + tq * 8);
        *(int4*)(betaT + ((long)z * TT + n0 + cl) * TT + m0 + tq * 8) = v;
    }
}

// ---------------------------------------------------------------------------
// Unified PV, full-D tile. zz<8: v-attends-a (P=beta, sums=rs, V=a2T,
// resid=v_fea); zz>=8: a-attends-v (P=betaT, sums=cs, V=v1T, resid=a_fea).
// BM=128, BN=256(=D), K=TT. 512 threads = 8 waves (2x4). (R5 verified.)
// ---------------------------------------------------------------------------
__global__ __launch_bounds__(512)
void pv_kernel(const u16* __restrict__ beta, const u16* __restrict__ betaT,
               const u16* __restrict__ a2T, const u16* __restrict__ v1T,
               const float* __restrict__ rs, const float* __restrict__ cs,
               const float* __restrict__ thrp,
               const float* __restrict__ v_fea, const float* __restrict__ a_fea,
               u16* __restrict__ yvin, u16* __restrict__ yain)
{
    __shared__ __align__(16) u16 A_s[128 * 32], B_s[256 * 32];
    __shared__ float sthr[128], sA[128], ssum[128];
    const int zz = blockIdx.x;
    const int m0 = blockIdx.y * 128;
    const int z = zz & 7;
    const bool av = zz >= 8;
    const u16* P      = av ? betaT : beta;
    const u16* VT     = av ? v1T : a2T;
    const float* sums = av ? cs : rs;
    const float* resid = av ? a_fea : v_fea;
    u16* outb         = av ? yain : yvin;

    const int tid = threadIdx.x, lane = tid & 63, w = tid >> 6;
    const int wy = w >> 2, wx = w & 3;
    const float thr = thrp[0] * 10.0f / (float)TT;
    if (tid < 128) {
        const float s = sums[(long)z * TT + m0 + tid];
        sA[tid] = s; sthr[tid] = thr * (s + EPSF); ssum[tid] = 0.f;
    }
    __syncthreads();
    f32x4 acc[4][4] = {};
    float rpart = 0.f;
    const int arow = tid >> 2, aq = tid & 3;          // A: 128 rows x 4 chunks
    const u16* Pp = P + ((long)z * TT + m0 + arow) * TT + aq * 8;
    const u16* V0 = VT + (long)z * DD * TT + (long)arow * TT + aq * 8;
    const u16* V1 = V0 + (long)128 * TT;
    const int da  = swz(frag_dst(arow, aq * 8));
    const int db1 = swz(frag_dst(arow + 128, aq * 8));

    int4 Ar  = *(const int4*)(Pp);
    int4 Br0 = *(const int4*)(V0);
    int4 Br1 = *(const int4*)(V1);

    for (int k0 = 0; k0 < TT; k0 += 32) {
        // consume prefetched regs: threshold A, copy B
        union { int4 v; u16 us[8]; } U;
        U.v = Ar;
        const float ct = sthr[arow];
        float ss = 0.f;
        #pragma unroll
        for (int t = 0; t < 8; ++t) {
            const float v = bf2f(U.us[t]);
            if (v > ct) ss += v; else U.us[t] = 0;
        }
        rpart += ss;
        *(int4*)(A_s + da) = U.v;
        *(int4*)(B_s + da) = Br0;
        *(int4*)(B_s + db1) = Br1;
        __syncthreads();
        // prefetch k0+32 (last iter: harmless re-load of same address)
        const int kn = (k0 + 32 < TT) ? (k0 + 32) : k0;
        Ar  = *(const int4*)(Pp + kn);
        Br0 = *(const int4*)(V0 + kn);
        Br1 = *(const int4*)(V1 + kn);
        // fragments + MFMA
        short8 a[4], b[4];
        #pragma unroll
        for (int i = 0; i < 4; ++i)
            a[i] = *(const short8*)(A_s + swz(((wy * 4 + i) * 64 + lane) * 8));
        #pragma unroll
        for (int j = 0; j < 4; ++j)
            b[j] = *(const short8*)(B_s + swz(((wx * 4 + j) * 64 + lane) * 8));
        #pragma unroll
        for (int i = 0; i < 4; ++i)
            #pragma unroll
            for (int j = 0; j < 4; ++j)
                acc[i][j] = __builtin_amdgcn_mfma_f32_16x16x32_bf16(a[i], b[j], acc[i][j], 0, 0, 0);
        __syncthreads();
    }
    atomicAdd(&ssum[arow], rpart);
    __syncthreads();

    const int quad = lane >> 4, col = lane & 15;
    #pragma unroll
    for (int i = 0; i < 4; ++i)
        #pragma unroll
        for (int j = 0; j < 4; ++j) {
            const int c = (wx * 4 + j) * 16 + col;
            #pragma unroll
            for (int r = 0; r < 4; ++r) {
                const int lrow = (wy * 4 + i) * 16 + quad * 4 + r;
                const int row = m0 + lrow;
                const float inv = 1.0f / (ssum[lrow] + EPSF * (sA[lrow] + EPSF));
                const float v = acc[i][j][r] * inv + resid[((long)z * TT + row) * DD + c];
                outb[((long)z * TT + row) * DD + c] = f2bf(v);
            }
        }
}

// ---------------------------------------------------------------------------
// FC: y = relu(yin @ Wfc^T), bf16 out. 512 threads = 8 waves (2 wy x 4 wx),
// BM=128, BN=64 -- same wave re-tile that took score 152->108 us.
// z selects branch via fixed strides. Math bit-identical to 256-thr version.
// ---------------------------------------------------------------------------
__global__ __launch_bounds__(512)
void fc_kernel(const u16* __restrict__ Ain, const u16* __restrict__ Wb,
               u16* __restrict__ Cb)
{
    const int z = blockIdx.z;
    const u16* A = Ain + (size_t)z * (size_t)NBATCH * TT * DD;
    const u16* B = Wb + (size_t)z * DD * DD;
    u16* C = Cb + (size_t)z * (size_t)NBATCH * TT * DD;
    __shared__ __align__(16) u16 A_s[128 * 32], B_s[64 * 32];
    const int m0 = blockIdx.y * 128, n0 = blockIdx.x * 64;
    const int tid = threadIdx.x, lane = tid & 63, w = tid >> 6;
    const int wy = w >> 2, wx = w & 3;
    f32x4 acc[4] = {};

    const int prow = tid >> 2, pq = tid & 3;
    const int dA = swz(frag_dst(prow, pq * 8));
    const u16* gA = A + (long)(m0 + prow) * DD + pq * 8;
    const int brow = (tid & 255) >> 2, bq = tid & 3;
    const int dB = swz(frag_dst(brow, bq * 8));
    const u16* gB = B + (long)(n0 + brow) * DD + bq * 8;

    int4 rA = *(const int4*)(gA);
    int4 rB = *(const int4*)(gB);

    for (int k0 = 0; k0 < DD; k0 += 32) {
        *(int4*)(A_s + dA) = rA;
        if (tid < 256) *(int4*)(B_s + dB) = rB;
        __syncthreads();
        const int kn = (k0 + 32 < DD) ? k0 + 32 : 0;
        rA = *(const int4*)(gA + kn);
        rB = *(const int4*)(gB + kn);
        short8 a[4], b;
        #pragma unroll
        for (int i = 0; i < 4; ++i)
            a[i] = *(const short8*)(A_s + swz(((wy * 4 + i) * 64 + lane) * 8));
        b = *(const short8*)(B_s + swz((wx * 64 + lane) * 8));
        #pragma unroll
        for (int i = 0; i < 4; ++i)
            acc[i] = __builtin_amdgcn_mfma_f32_16x16x32_bf16(a[i], b, acc[i], 0, 0, 0);
        __syncthreads();
    }
    const int quad = lane >> 4, col = lane & 15;
    const int c = n0 + wx * 16 + col;
    #pragma unroll
    for (int i = 0; i < 4; ++i) {
        #pragma unroll
        for (int r = 0; r < 4; ++r) {
            const int row = m0 + wy * 64 + i * 16 + quad * 4 + r;
            C[(long)row * DD + c] = f2bf(fmaxf(acc[i][r], 0.f));
        }
    }
}

// ---------------------------------------------------------------------------
// Exact fp32 pred: recompute v2[0,t], a1[0,t] and their dot; compare.
// ---------------------------------------------------------------------------
__global__ __launch_bounds__(256)
void pred_exact(const float* __restrict__ vf, const float* __restrict__ af,
                const float* __restrict__ Wv2, const float* __restrict__ Wa1,
                const float* __restrict__ cs, const float* __restrict__ thrp,
                float* __restrict__ pred)
{
    __shared__ float vs[8][260];
    __shared__ float as_[8][260];
    __shared__ float red[4][8];
    const int t0 = blockIdx.x * 8;
    const int tid = threadIdx.x;
    {
        const int i = tid >> 5, c = (tid & 31) * 8;
        *(float4*)&vs[i][c] = *(const float4*)(vf + (long)(t0 + i) * DD + c);
        *(float4*)&vs[i][c + 4] = *(const float4*)(vf + (long)(t0 + i) * DD + c + 4);
        *(float4*)&as_[i][c] = *(const float4*)(af + (long)(t0 + i) * DD + c);
        *(float4*)&as_[i][c + 4] = *(const float4*)(af + (long)(t0 + i) * DD + c + 4);
    }
    __syncthreads();
    const int j = tid;
    float av[8] = {0.f}, aa[8] = {0.f};
    for (int k = 0; k < DD; k += 4) {
        const float4 wv = *(const float4*)(Wv2 + (long)j * DD + k);
        const float4 wa = *(const float4*)(Wa1 + (long)j * DD + k);
        #pragma unroll
        for (int i = 0; i < 8; ++i) {
            const float4 x = *(const float4*)&vs[i][k];
            av[i] += wv.x * x.x + wv.y * x.y + wv.z * x.z + wv.w * x.w;
            const float4 y = *(const float4*)&as_[i][k];
            aa[i] += wa.x * y.x + wa.y * y.y + wa.z * y.z + wa.w * y.w;
        }
    }
    float p[8];
    #pragma unroll
    for (int i = 0; i < 8; ++i)
        p[i] = fmaxf(av[i], 0.f) * fmaxf(aa[i], 0.f);
    #pragma unroll
    for (int off = 32; off > 0; off >>= 1)
        #pragma unroll
        for (int i = 0; i < 8; ++i) p[i] += __shfl_xor(p[i], off);
    const int lane = tid & 63, wv_ = tid >> 6;
    if (lane == 0)
        #pragma unroll
        for (int i = 0; i < 8; ++i) red[wv_][i] = p[i];
    __syncthreads();
    if (tid < 8) {
        float d = red[0][tid] + red[1][tid] + red[2][tid] + red[3][tid];
        d = fmaxf(d * (1.f / 16.f), 0.f);
        const float thr = thrp[0] * 10.0f / (float)TT;
        pred[t0 + tid] = (d > thr * (cs[t0 + tid] + EPSF)) ? 1.0f : 0.0f;
    }
}

// ---------------------------------------------------------------------------
// Split v_fea/a_fea fp32 -> bf16 h/l pairs. grid.y: 0=v, 1=a.
// ---------------------------------------------------------------------------
__global__ __launch_bounds__(256)
void split_feat(const float* __restrict__ vf, const float* __restrict__ af,
                u16* __restrict__ vfh, u16* __restrict__ vfl,
                u16* __restrict__ afh, u16* __restrict__ afl)
{
    const long i4 = ((long)blockIdx.x * 256 + threadIdx.x) * 4;
    const float* src = blockIdx.y ? af : vf;
    u16* dh = blockIdx.y ? afh : vfh;
    u16* dl = blockIdx.y ? afl : vfl;
    float4 a = *(const float4*)(src + i4);
    ushort4 h4, l4; u16 h;
    h = f2bf(a.x); h4.x = h; l4.x = f2bf(a.x - bf2f(h));
    h = f2bf(a.y); h4.y = h; l4.y = f2bf(a.y - bf2f(h));
    h = f2bf(a.z); h4.z = h; l4.z = f2bf(a.z - bf2f(h));
    h = f2bf(a.w); h4.w = h; l4.w = f2bf(a.w - bf2f(h));
    *(ushort4*)(dh + i4) = h4;
    *(ushort4*)(dl + i4) = l4;
}

// ---------------------------------------------------------------------------
// Split/convert 6 weight matrices into Wsp: [Wv1h Wv1l Wv2h Wv2l Wa1h Wa1l
// Wa2h Wa2l Wvfcb Wafcb], each DD*DD. grid.y = task 0..5.
// ---------------------------------------------------------------------------
__global__ __launch_bounds__(256)
void split_w(const float* __restrict__ w0, const float* __restrict__ w1,
             const float* __restrict__ w2, const float* __restrict__ w3,
             const float* __restrict__ w4, const float* __restrict__ w5,
             u16* __restrict__ out)
{
    const int t = blockIdx.y;
    const float* w = (t == 0) ? w0 : (t == 1) ? w1 : (t == 2) ? w2
                   : (t == 3) ? w3 : (t == 4) ? w4 : w5;
    const int i4 = (blockIdx.x * 256 + threadIdx.x) * 4;
    float4 a = *(const float4*)(w + i4);
    if (t < 4) {
        u16* oh = out + (size_t)t * 2 * DD * DD;
        u16* ol = oh + DD * DD;
        ushort4 h4, l4; u16 h;
        h = f2bf(a.x); h4.x = h; l4.x = f2bf(a.x - bf2f(h));
        h = f2bf(a.y); h4.y = h; l4.y = f2bf(a.y - bf2f(h));
        h = f2bf(a.z); h4.z = h; l4.z = f2bf(a.z - bf2f(h));
        h = f2bf(a.w); h4.w = h; l4.w = f2bf(a.w - bf2f(h));
        *(ushort4*)(oh + i4) = h4;
        *(ushort4*)(ol + i4) = l4;
    } else {
        u16* ob = out + (size_t)8 * DD * DD + (size_t)(t - 4) * DD * DD;
        ushort4 o;
        o.x = f2bf(a.x); o.y = f2bf(a.y); o.z = f2bf(a.z); o.w = f2bf(a.w);
        *(ushort4*)(ob + i4) = o;
    }
}

// ---------------------------------------------------------------------------
// LayerNorm both branches + fuse. 4 rows/block, 1 wave per row. bf16 in,
// fp32 out.
// ---------------------------------------------------------------------------
__global__ __launch_bounds__(256)
void ln_fuse_kernel(const u16* __restrict__ yv, const u16* __restrict__ ya,
                    const float* __restrict__ g, const float* __restrict__ b,
                    float* __restrict__ fuse, float* __restrict__ vpsp,
                    float* __restrict__ apsp)
{
    const long row = (long)blockIdx.x * 4 + (threadIdx.x >> 6);
    const int lane = threadIdx.x & 63;
    const ushort4 hv = *(const ushort4*)(yv + row * DD + lane * 4);
    const ushort4 ha = *(const ushort4*)(ya + row * DD + lane * 4);
    const float xv0 = bf2f(hv.x), xv1 = bf2f(hv.y), xv2 = bf2f(hv.z), xv3 = bf2f(hv.w);
    const float xa0 = bf2f(ha.x), xa1 = bf2f(ha.y), xa2 = bf2f(ha.z), xa3 = bf2f(ha.w);
    float sv = xv0 + xv1 + xv2 + xv3;
    float sa = xa0 + xa1 + xa2 + xa3;
    #pragma unroll
    for (int off = 32; off > 0; off >>= 1) {
        sv += __shfl_xor(sv, off);
        sa += __shfl_xor(sa, off);
    }
    const float mv = sv * (1.f / 256.f);
    const float ma = sa * (1.f / 256.f);
    const float dv0 = xv0 - mv, dv1 = xv1 - mv, dv2 = xv2 - mv, dv3 = xv3 - mv;
    const float da0 = xa0 - ma, da1 = xa1 - ma, da2 = xa2 - ma, da3 = xa3 - ma;
    float qv = dv0 * dv0 + dv1 * dv1 + dv2 * dv2 + dv3 * dv3;
    float qa = da0 * da0 + da1 * da1 + da2 * da2 + da3 * da3;
    #pragma unroll
    for (int off = 32; off > 0; off >>= 1) {
        qv += __shfl_xor(qv, off);
        qa += __shfl_xor(qa, off);
    }
    const float rv = rsqrtf(qv * (1.f / 256.f) + 1e-6f);
    const float ra = rsqrtf(qa * (1.f / 256.f) + 1e-6f);
    const float4 gg = *(const float4*)(g + lane * 4);
    const float4 bb = *(const float4*)(b + lane * 4);
    float4 ov, oa, of;
    ov.x = dv0 * rv * gg.x + bb.x; ov.y = dv1 * rv * gg.y + bb.y;
    ov.z = dv2 * rv * gg.z + bb.z; ov.w = dv3 * rv * gg.w + bb.w;
    oa.x = da0 * ra * gg.x + bb.x; oa.y = da1 * ra * gg.y + bb.y;
    oa.z = da2 * ra * gg.z + bb.z; oa.w = da3 * ra * gg.w + bb.w;
    of.x = 0.5f * (ov.x + oa.x); of.y = 0.5f * (ov.y + oa.y);
    of.z = 0.5f * (ov.z + oa.z); of.w = 0.5f * (ov.w + oa.w);
    *(float4*)(vpsp + row * DD + lane * 4) = ov;
    *(float4*)(apsp + row * DD + lane * 4) = oa;
    *(float4*)(fuse + row * DD + lane * 4) = of;
}

extern "C" void kernel_launch(void* const* d_in, const int* in_sizes, int n_in,
                              void* d_out, int out_size, void* d_ws, size_t ws_size,
                              hipStream_t stream)
{
    const float* a_fea = (const float*)d_in[0];
    const float* v_fea = (const float*)d_in[1];
    const float* thrp  = (const float*)d_in[2];
    const float* Wv1   = (const float*)d_in[3];
    const float* Wv2   = (const float*)d_in[4];
    const float* Wvfc  = (const float*)d_in[5];
    const float* Wa1   = (const float*)d_in[6];
    const float* Wa2   = (const float*)d_in[7];
    const float* Wafc  = (const float*)d_in[8];
    const float* lng   = (const float*)d_in[9];
    const float* lnb   = (const float*)d_in[10];

    const long MT = (long)NBATCH * TT;
    float* out_fuse = (float*)d_out;
    float* out_vpsp = out_fuse + MT * DD;
    float* out_apsp = out_vpsp + MT * DD;
    float* out_pred = out_apsp + MT * DD;

    // ws: v2h v2l a1h a1l yvin yain v1T a2T (8xfb) | rs cs | Wsp(10xDDDD) |
    //     beta(67MB) betaT(67MB). vfh/vfl/afh/afl (transient) alias beta's
    //     front (dead before score writes beta). yvb/yab (fc bf16 out)
    //     alias slots 0-1 (v2h/v2l, dead after score).
    char* ws = (char*)d_ws;
    const size_t fb = (size_t)MT * DD * sizeof(u16);
    const size_t sumB = (size_t)MT * sizeof(float);
    u16* v2h  = (u16*)(ws + 0 * fb);
    u16* v2l  = (u16*)(ws + 1 * fb);
    u16* a1h  = (u16*)(ws + 2 * fb);
    u16* a1l  = (u16*)(ws + 3 * fb);
    u16* yvin = (u16*)(ws + 4 * fb);
    u16* yain = (u16*)(ws + 5 * fb);
    u16* v1T  = (u16*)(ws + 6 * fb);
    u16* a2T  = (u16*)(ws + 7 * fb);
    char* p = ws + 8 * fb;
    float* rs = (float*)(p + 0 * sumB);
    float* cs = (float*)(p + 1 * sumB);
    u16* Wsp  = (u16*)(p + 2 * sumB);
    char* q = p + 2 * sumB + 10 * DD * DD * sizeof(u16);
    const size_t betaB = (size_t)NBATCH * TT * TT * sizeof(u16);   // 67 MB
    u16* beta  = (u16*)q;
    u16* betaT = (u16*)(q + betaB);
    u16* vfh = (u16*)q;            // transient splits, dead before score
    u16* vfl = vfh + MT * DD;
    u16* afh = vfl + MT * DD;
    u16* afl = afh + MT * DD;
    u16* yvb = (u16*)(ws + 0 * fb);        // fc bf16 out, z-stride MT*DD
    u16* yab = yvb + (size_t)MT * DD;

    hipMemsetAsync(rs, 0, 2 * sumB, stream);

    const dim3 blk(256, 1, 1);

    split_feat<<<dim3((unsigned)(MT * DD / 1024), 2, 1), blk, 0, stream>>>(
        v_fea, a_fea, vfh, vfl, afh, afl);
    split_w<<<dim3(DD * DD / 1024, 6, 1), blk, 0, stream>>>(
        Wv1, Wv2, Wa1, Wa2, Wvfc, Wafc, Wsp);

    // 512-thread proj (8 waves), BM=128
    proj_kernel<<<dim3(DD / 64, (unsigned)(MT / 128), 4), dim3(512, 1, 1), 0, stream>>>(
        vfh, vfl, afh, afl, Wsp, v2h, v2l, a1h, a1l, v1T, a2T);

    // 512-thread score (8 waves), XCD-affine tile remap inside kernel
    score_kernel<<<dim3(TT / 128, TT / 128, NBATCH), dim3(512, 1, 1), 0, stream>>>(
        v2h, v2l, a1h, a1l, beta, betaT, rs, cs);
    pred_exact<<<dim3(TT / 8, 1, 1), blk, 0, stream>>>(
        v_fea, a_fea, Wv2, Wa1, cs, thrp, out_pred);

    // grid: x = zz (batch+dir, XCD-affine), y = m0 tile; 512 threads
    pv_kernel<<<dim3(2 * NBATCH, TT / 128, 1), dim3(512, 1, 1), 0, stream>>>(
        beta, betaT, a2T, v1T, rs, cs, thrp, v_fea, a_fea, yvin, yain);

    // 512-thread fc (8 waves)
    fc_kernel<<<dim3(DD / 64, (unsigned)(MT / 128), 2), dim3(512, 1, 1), 0, stream>>>(
        yvin, Wsp + 8 * DD * DD, yvb);
    ln_fuse_kernel<<<dim3((unsigned)(MT / 4), 1, 1), blk, 0, stream>>>(
        yvb, yab, lng, lnb, out_fuse, out_vpsp, out_apsp);
}

// Round 8
// 400.628 us; speedup vs baseline: 1.0625x; 1.0625x over previous
//
#include <hip/hip_runtime.h>
#include <math.h>

#define TT 2048
#define DD 256
#define NBATCH 8
#define EPSF 1e-8f

typedef unsigned short u16;
typedef __attribute__((ext_vector_type(8))) short short8;
typedef __attribute__((ext_vector_type(4))) float f32x4;

__device__ __forceinline__ u16 f2bf(float x) {
    unsigned int u = __builtin_bit_cast(unsigned int, x);
    u += 0x7fffu + ((u >> 16) & 1u);
    return (u16)(u >> 16);
}
__device__ __forceinline__ float bf2f(u16 h) {
    return __builtin_bit_cast(float, (unsigned int)h << 16);
}

// MFMA-fragment LDS index for a [rows x 32k] bf16 tile:
// elem(row,k) -> (((row>>4)*4+(k>>3))*16+(row&15))*8+(k&7)
// Fragment read for 16-row subtile t is ds_read_b128 at (t*64+lane)*8.
__device__ __forceinline__ int frag_dst(int row, int k) {
    return (((row >> 4) * 4 + (k >> 3)) * 16 + (row & 15)) * 8 + (k & 7);
}

// Address-pure bank swizzle (u16 index), applied to both write and read.
__device__ __forceinline__ int swz(int i) { return i ^ ((i >> 2) & 32); }

template<int BR>
__device__ __forceinline__ void stage_tile(const u16* __restrict__ g, u16* s,
                                           int row0, int k0, int ldk, int tid)
{
    #pragma unroll
    for (int i = 0; i < BR / 64; ++i) {
        const int c = tid + 256 * i;
        const int row = c >> 2, q = c & 3;
        *(int4*)(s + swz(frag_dst(row, q * 8))) =
            *(const int4*)(g + (long)(row0 + row) * ldk + k0 + q * 8);
    }
}

// ---------------------------------------------------------------------------
// Combined projections. z = 0:v2(split h/l) 1:a1(split h/l)
//                        2:v1 -> v1T (register-transposed bf16)
//                        3:a2 -> a2T
// 3-term split-bf16 MFMA (rel err ~3e-6). 512 threads = 8 waves (2 wy x
// 4 wx), BM=128, BN=64. Outputs bit-identical to the 256-thread version.
// ---------------------------------------------------------------------------
__global__ __launch_bounds__(512)
void proj_kernel(const u16* __restrict__ vfh, const u16* __restrict__ vfl,
                 const u16* __restrict__ afh, const u16* __restrict__ afl,
                 const u16* __restrict__ Wsp,
                 u16* __restrict__ v2h, u16* __restrict__ v2l,
                 u16* __restrict__ a1h, u16* __restrict__ a1l,
                 u16* __restrict__ v1T, u16* __restrict__ a2T)
{
    const int zz = blockIdx.z;
    const u16* Ah = (zz == 1 || zz == 3) ? afh : vfh;
    const u16* Al = (zz == 1 || zz == 3) ? afl : vfl;
    const int widx = (zz == 0) ? 2 : (zz == 1) ? 4 : (zz == 2) ? 0 : 6;
    const u16* Bh = Wsp + widx * DD * DD;
    const u16* Bl = Bh + DD * DD;
    const bool split = zz < 2;
    u16* Oh = (zz == 0) ? v2h : a1h;
    u16* Ol = (zz == 0) ? v2l : a1l;
    u16* OT = (zz == 2) ? v1T : a2T;

    __shared__ __align__(16) u16 Ah_s[128 * 32], Al_s[128 * 32];
    __shared__ __align__(16) u16 Bh_s[64 * 32], Bl_s[64 * 32];
    const int m0 = blockIdx.y * 128, n0 = blockIdx.x * 64;
    const int tid = threadIdx.x, lane = tid & 63, w = tid >> 6;
    const int wy = w >> 2, wx = w & 3;
    f32x4 acc[4] = {};

    // A staging: all 512 threads, 1 chunk per tile (row tid>>2, q tid&3)
    const int prow = tid >> 2, pq = tid & 3;
    const int dA = swz(frag_dst(prow, pq * 8));
    const u16* gAh = Ah + (long)(m0 + prow) * DD + pq * 8;
    const u16* gAl = Al + (long)(m0 + prow) * DD + pq * 8;
    // B staging: tid<256 -> Bh, tid>=256 -> Bl (row (tid&255)>>2)
    const int brow = (tid & 255) >> 2, bq = tid & 3;
    const int dB = swz(frag_dst(brow, bq * 8));
    const u16* gB = ((tid < 256) ? Bh : Bl) + (long)(n0 + brow) * DD + bq * 8;
    u16* sB = (tid < 256) ? Bh_s : Bl_s;

    int4 rAh = *(const int4*)(gAh);
    int4 rAl = *(const int4*)(gAl);
    int4 rB  = *(const int4*)(gB);

    for (int k0 = 0; k0 < DD; k0 += 32) {
        *(int4*)(Ah_s + dA) = rAh;
        *(int4*)(Al_s + dA) = rAl;
        *(int4*)(sB + dB)   = rB;
        __syncthreads();
        const int kn = (k0 + 32 < DD) ? k0 + 32 : 0;
        rAh = *(const int4*)(gAh + kn);
        rAl = *(const int4*)(gAl + kn);
        rB  = *(const int4*)(gB + kn);
        short8 ah[4], al[4], bh, bl;
        #pragma unroll
        for (int i = 0; i < 4; ++i) {
            ah[i] = *(const short8*)(Ah_s + swz(((wy * 4 + i) * 64 + lane) * 8));
            al[i] = *(const short8*)(Al_s + swz(((wy * 4 + i) * 64 + lane) * 8));
        }
        bh = *(const short8*)(Bh_s + swz((wx * 64 + lane) * 8));
        bl = *(const short8*)(Bl_s + swz((wx * 64 + lane) * 8));
        #pragma unroll
        for (int i = 0; i < 4; ++i) {
            acc[i] = __builtin_amdgcn_mfma_f32_16x16x32_bf16(ah[i], bl, acc[i], 0, 0, 0);
            acc[i] = __builtin_amdgcn_mfma_f32_16x16x32_bf16(al[i], bh, acc[i], 0, 0, 0);
            acc[i] = __builtin_amdgcn_mfma_f32_16x16x32_bf16(ah[i], bh, acc[i], 0, 0, 0);
        }
        __syncthreads();
    }
    const int quad = lane >> 4, col = lane & 15;
    const int c = n0 + wx * 16 + col;
    #pragma unroll
    for (int i = 0; i < 4; ++i) {
        const int rbase = m0 + wy * 64 + i * 16 + quad * 4;
        if (split) {
            #pragma unroll
            for (int r = 0; r < 4; ++r) {
                const float v = fmaxf(acc[i][r], 0.f);
                const u16 h = f2bf(v);
                Oh[(long)(rbase + r) * DD + c] = h;
                Ol[(long)(rbase + r) * DD + c] = f2bf(v - bf2f(h));
            }
        } else {
            // transposed: OT[b][d=c][t]; 4 consecutive t = one b64 store
            short4 pk;
            pk.x = (short)f2bf(fmaxf(acc[i][0], 0.f));
            pk.y = (short)f2bf(fmaxf(acc[i][1], 0.f));
            pk.z = (short)f2bf(fmaxf(acc[i][2], 0.f));
            pk.w = (short)f2bf(fmaxf(acc[i][3], 0.f));
            const int b = rbase >> 11, t = rbase & (TT - 1);
            *(short4*)(OT + ((long)b * DD + c) * TT + t) = pk;
        }
    }
}

// ---------------------------------------------------------------------------
// Scores: beta(bf16) = relu(v2.a1/16), 3-term split MFMA. BM=BN=128.
// 512 threads = 8 waves (2 wy x 4 wx), verified R5 pipeline, natural
// block mapping (R7's XCD-affine remap measured: FETCH -60% but dur +30%
// -- score is latency-bound, not BW-bound; remap retired).
// ---------------------------------------------------------------------------
__global__ __launch_bounds__(512)
void score_kernel(const u16* __restrict__ v2h, const u16* __restrict__ v2l,
                  const u16* __restrict__ a1h, const u16* __restrict__ a1l,
                  u16* __restrict__ beta, u16* __restrict__ betaT,
                  float* __restrict__ rs, float* __restrict__ cs)
{
    // S serves as: 4 staging tiles (32 KB) in the K-loop, then the 128x128
    // store buffer (stride 136, 34 KB) in the epilogue.
    __shared__ __align__(16) u16 S[128 * 136];
    u16* Ah_s = S;
    u16* Al_s = S + 4096;
    u16* Bh_s = S + 8192;
    u16* Bl_s = S + 12288;
    const int z = blockIdx.z;
    const int m0 = blockIdx.y * 128, n0 = blockIdx.x * 128;
    const int tid = threadIdx.x, lane = tid & 63, w = tid >> 6;
    const int wy = w >> 2, wx = w & 3;              // 2 x 4 waves
    const long zoff = (long)z * TT * DD;
    f32x4 acc[4][2] = {};

    // staging: 512 threads, one 16B chunk per tile per thread
    const int prow = tid >> 2, pq = tid & 3;        // row 0..127, k-chunk 0..3
    const int d0 = swz(frag_dst(prow, pq * 8));
    const u16* gAh = v2h + zoff + (long)(m0 + prow) * DD + pq * 8;
    const u16* gAl = v2l + zoff + (long)(m0 + prow) * DD + pq * 8;
    const u16* gBh = a1h + zoff + (long)(n0 + prow) * DD + pq * 8;
    const u16* gBl = a1l + zoff + (long)(n0 + prow) * DD + pq * 8;

    int4 rAh = *(const int4*)(gAh);
    int4 rAl = *(const int4*)(gAl);
    int4 rBh = *(const int4*)(gBh);
    int4 rBl = *(const int4*)(gBl);

    for (int k0 = 0; k0 < DD; k0 += 32) {
        *(int4*)(Ah_s + d0) = rAh;
        *(int4*)(Al_s + d0) = rAl;
        *(int4*)(Bh_s + d0) = rBh;
        *(int4*)(Bl_s + d0) = rBl;
        __syncthreads();
        // prefetch k0+32 (last iter: harmless reload of k=0)
        const int kn = (k0 + 32 < DD) ? k0 + 32 : 0;
        rAh = *(const int4*)(gAh + kn);
        rAl = *(const int4*)(gAl + kn);
        rBh = *(const int4*)(gBh + kn);
        rBl = *(const int4*)(gBl + kn);
        short8 ah[4], al[4], bh[2], bl[2];
        #pragma unroll
        for (int i = 0; i < 4; ++i) {
            ah[i] = *(const short8*)(Ah_s + swz(((wy * 4 + i) * 64 + lane) * 8));
            al[i] = *(const short8*)(Al_s + swz(((wy * 4 + i) * 64 + lane) * 8));
        }
        #pragma unroll
        for (int j = 0; j < 2; ++j) {
            bh[j] = *(const short8*)(Bh_s + swz(((wx * 2 + j) * 64 + lane) * 8));
            bl[j] = *(const short8*)(Bl_s + swz(((wx * 2 + j) * 64 + lane) * 8));
        }
        #pragma unroll
        for (int i = 0; i < 4; ++i)
            #pragma unroll
            for (int j = 0; j < 2; ++j) {
                acc[i][j] = __builtin_amdgcn_mfma_f32_16x16x32_bf16(ah[i], bl[j], acc[i][j], 0, 0, 0);
                acc[i][j] = __builtin_amdgcn_mfma_f32_16x16x32_bf16(al[i], bh[j], acc[i][j], 0, 0, 0);
                acc[i][j] = __builtin_amdgcn_mfma_f32_16x16x32_bf16(ah[i], bh[j], acc[i][j], 0, 0, 0);
            }
        __syncthreads();
    }

    const int quad = lane >> 4, col = lane & 15;
    const float scale = 1.f / 16.f;
    #pragma unroll
    for (int i = 0; i < 4; ++i)
        #pragma unroll
        for (int j = 0; j < 2; ++j)
            #pragma unroll
            for (int r = 0; r < 4; ++r)
                acc[i][j][r] = fmaxf(acc[i][j][r] * scale, 0.f);

    // beta row-major: stage into S[rl][cl] (stride 136), coalesced int4 out
    #pragma unroll
    for (int i = 0; i < 4; ++i) {
        const int rl = (wy * 4 + i) * 16 + quad * 4;
        #pragma unroll
        for (int j = 0; j < 2; ++j) {
            const int cl = (wx * 2 + j) * 16 + col;
            #pragma unroll
            for (int r = 0; r < 4; ++r)
                S[(rl + r) * 136 + cl] = f2bf(acc[i][j][r]);
        }
    }
    __syncthreads();
    #pragma unroll
    for (int it = 0; it < 4; ++it) {
        const int idx = tid + 512 * it;
        const int rl = idx >> 4, cq = idx & 15;
        const int4 v = *(const int4*)(S + rl * 136 + cq * 8);
        *(int4*)(beta + ((long)z * TT + m0 + rl) * TT + n0 + cq * 8) = v;
    }
    // row sums (fp32-exact atomics): wave partial = its 32 cols
    #pragma unroll
    for (int i = 0; i < 4; ++i)
        #pragma unroll
        for (int r = 0; r < 4; ++r) {
            float rp = acc[i][0][r] + acc[i][1][r];
            rp += __shfl_xor(rp, 1); rp += __shfl_xor(rp, 2);
            rp += __shfl_xor(rp, 4); rp += __shfl_xor(rp, 8);
            if (col == 0) {
                const int row = m0 + (wy * 4 + i) * 16 + quad * 4 + r;
                atomicAdd(&rs[(long)z * TT + row], rp);
            }
        }
    // col sums: wave partial = its 64 rows
    #pragma unroll
    for (int j = 0; j < 2; ++j) {
        float cp = 0.f;
        #pragma unroll
        for (int i = 0; i < 4; ++i)
            #pragma unroll
            for (int r = 0; r < 4; ++r) cp += acc[i][j][r];
        cp += __shfl_xor(cp, 16); cp += __shfl_xor(cp, 32);
        if (lane < 16) {
            const int c = n0 + (wx * 2 + j) * 16 + col;
            atomicAdd(&cs[(long)z * TT + c], cp);
        }
    }
    // betaT via LDS transpose: S[cl][rl] (stride 136), coalesced int4 out
    __syncthreads();
    #pragma unroll
    for (int i = 0; i < 4; ++i)
        #pragma unroll
        for (int j = 0; j < 2; ++j) {
            const int cl = (wx * 2 + j) * 16 + col;
            const int rl = (wy * 4 + i) * 16 + quad * 4;
            short4 pk;
            pk.x = (short)f2bf(acc[i][j][0]);
            pk.y = (short)f2bf(acc[i][j][1]);
            pk.z = (short)f2bf(acc[i][j][2]);
            pk.w = (short)f2bf(acc[i][j][3]);
            *(short4*)(S + cl * 136 + rl) = pk;
        }
    __syncthreads();
    #pragma unroll
    for (int it = 0; it < 4; ++it) {
        const int idx = tid + 512 * it;
        const int cl = idx >> 4, tq = idx & 15;
        const int4 v = *(const int4*)(S + cl * 136 + tq * 8);
        *(int4*)(betaT + ((long)z * TT + n0 + cl) * TT + m0 + tq * 8) = v;
    }
}

// ---------------------------------------------------------------------------
// Unified PV, full-D tile. zz<8: v-attends-a (P=beta, sums=rs, V=a2T,
// resid=v_fea); zz>=8: a-attends-v (P=betaT, sums=cs, V=v1T, resid=a_fea).
// BM=128, BN=256(=D), K=TT. 512 threads = 8 waves (2x4). (R5 verified.)
// ---------------------------------------------------------------------------
__global__ __launch_bounds__(512)
void pv_kernel(const u16* __restrict__ beta, const u16* __restrict__ betaT,
               const u16* __restrict__ a2T, const u16* __restrict__ v1T,
               const float* __restrict__ rs, const float* __restrict__ cs,
               const float* __restrict__ thrp,
               const float* __restrict__ v_fea, const float* __restrict__ a_fea,
               u16* __restrict__ yvin, u16* __restrict__ yain)
{
    __shared__ __align__(16) u16 A_s[128 * 32], B_s[256 * 32];
    __shared__ float sthr[128], sA[128], ssum[128];
    const int zz = blockIdx.x;
    const int m0 = blockIdx.y * 128;
    const int z = zz & 7;
    const bool av = zz >= 8;
    const u16* P      = av ? betaT : beta;
    const u16* VT     = av ? v1T : a2T;
    const float* sums = av ? cs : rs;
    const float* resid = av ? a_fea : v_fea;
    u16* outb         = av ? yain : yvin;

    const int tid = threadIdx.x, lane = tid & 63, w = tid >> 6;
    const int wy = w >> 2, wx = w & 3;
    const float thr = thrp[0] * 10.0f / (float)TT;
    if (tid < 128) {
        const float s = sums[(long)z * TT + m0 + tid];
        sA[tid] = s; sthr[tid] = thr * (s + EPSF); ssum[tid] = 0.f;
    }
    __syncthreads();
    f32x4 acc[4][4] = {};
    float rpart = 0.f;
    const int arow = tid >> 2, aq = tid & 3;          // A: 128 rows x 4 chunks
    const u16* Pp = P + ((long)z * TT + m0 + arow) * TT + aq * 8;
    const u16* V0 = VT + (long)z * DD * TT + (long)arow * TT + aq * 8;
    const u16* V1 = V0 + (long)128 * TT;
    const int da  = swz(frag_dst(arow, aq * 8));
    const int db1 = swz(frag_dst(arow + 128, aq * 8));

    int4 Ar  = *(const int4*)(Pp);
    int4 Br0 = *(const int4*)(V0);
    int4 Br1 = *(const int4*)(V1);

    for (int k0 = 0; k0 < TT; k0 += 32) {
        // consume prefetched regs: threshold A, copy B
        union { int4 v; u16 us[8]; } U;
        U.v = Ar;
        const float ct = sthr[arow];
        float ss = 0.f;
        #pragma unroll
        for (int t = 0; t < 8; ++t) {
            const float v = bf2f(U.us[t]);
            if (v > ct) ss += v; else U.us[t] = 0;
        }
        rpart += ss;
        *(int4*)(A_s + da) = U.v;
        *(int4*)(B_s + da) = Br0;
        *(int4*)(B_s + db1) = Br1;
        __syncthreads();
        // prefetch k0+32 (last iter: harmless re-load of same address)
        const int kn = (k0 + 32 < TT) ? (k0 + 32) : k0;
        Ar  = *(const int4*)(Pp + kn);
        Br0 = *(const int4*)(V0 + kn);
        Br1 = *(const int4*)(V1 + kn);
        // fragments + MFMA
        short8 a[4], b[4];
        #pragma unroll
        for (int i = 0; i < 4; ++i)
            a[i] = *(const short8*)(A_s + swz(((wy * 4 + i) * 64 + lane) * 8));
        #pragma unroll
        for (int j = 0; j < 4; ++j)
            b[j] = *(const short8*)(B_s + swz(((wx * 4 + j) * 64 + lane) * 8));
        #pragma unroll
        for (int i = 0; i < 4; ++i)
            #pragma unroll
            for (int j = 0; j < 4; ++j)
                acc[i][j] = __builtin_amdgcn_mfma_f32_16x16x32_bf16(a[i], b[j], acc[i][j], 0, 0, 0);
        __syncthreads();
    }
    atomicAdd(&ssum[arow], rpart);
    __syncthreads();

    const int quad = lane >> 4, col = lane & 15;
    #pragma unroll
    for (int i = 0; i < 4; ++i)
        #pragma unroll
        for (int j = 0; j < 4; ++j) {
            const int c = (wx * 4 + j) * 16 + col;
            #pragma unroll
            for (int r = 0; r < 4; ++r) {
                const int lrow = (wy * 4 + i) * 16 + quad * 4 + r;
                const int row = m0 + lrow;
                const float inv = 1.0f / (ssum[lrow] + EPSF * (sA[lrow] + EPSF));
                const float v = acc[i][j][r] * inv + resid[((long)z * TT + row) * DD + c];
                outb[((long)z * TT + row) * DD + c] = f2bf(v);
            }
        }
}

// ---------------------------------------------------------------------------
// FC: y = relu(yin @ Wfc^T), bf16 out. 512 threads = 8 waves (2 wy x 4 wx),
// BM=128, BN=64. z selects branch via fixed strides.
// ---------------------------------------------------------------------------
__global__ __launch_bounds__(512)
void fc_kernel(const u16* __restrict__ Ain, const u16* __restrict__ Wb,
               u16* __restrict__ Cb)
{
    const int z = blockIdx.z;
    const u16* A = Ain + (size_t)z * (size_t)NBATCH * TT * DD;
    const u16* B = Wb + (size_t)z * DD * DD;
    u16* C = Cb + (size_t)z * (size_t)NBATCH * TT * DD;
    __shared__ __align__(16) u16 A_s[128 * 32], B_s[64 * 32];
    const int m0 = blockIdx.y * 128, n0 = blockIdx.x * 64;
    const int tid = threadIdx.x, lane = tid & 63, w = tid >> 6;
    const int wy = w >> 2, wx = w & 3;
    f32x4 acc[4] = {};

    const int prow = tid >> 2, pq = tid & 3;
    const int dA = swz(frag_dst(prow, pq * 8));
    const u16* gA = A + (long)(m0 + prow) * DD + pq * 8;
    const int brow = (tid & 255) >> 2, bq = tid & 3;
    const int dB = swz(frag_dst(brow, bq * 8));
    const u16* gB = B + (long)(n0 + brow) * DD + bq * 8;

    int4 rA = *(const int4*)(gA);
    int4 rB = *(const int4*)(gB);

    for (int k0 = 0; k0 < DD; k0 += 32) {
        *(int4*)(A_s + dA) = rA;
        if (tid < 256) *(int4*)(B_s + dB) = rB;
        __syncthreads();
        const int kn = (k0 + 32 < DD) ? k0 + 32 : 0;
        rA = *(const int4*)(gA + kn);
        rB = *(const int4*)(gB + kn);
        short8 a[4], b;
        #pragma unroll
        for (int i = 0; i < 4; ++i)
            a[i] = *(const short8*)(A_s + swz(((wy * 4 + i) * 64 + lane) * 8));
        b = *(const short8*)(B_s + swz((wx * 64 + lane) * 8));
        #pragma unroll
        for (int i = 0; i < 4; ++i)
            acc[i] = __builtin_amdgcn_mfma_f32_16x16x32_bf16(a[i], b, acc[i], 0, 0, 0);
        __syncthreads();
    }
    const int quad = lane >> 4, col = lane & 15;
    const int c = n0 + wx * 16 + col;
    #pragma unroll
    for (int i = 0; i < 4; ++i) {
        #pragma unroll
        for (int r = 0; r < 4; ++r) {
            const int row = m0 + wy * 64 + i * 16 + quad * 4 + r;
            C[(long)row * DD + c] = f2bf(fmaxf(acc[i][r], 0.f));
        }
    }
}

// ---------------------------------------------------------------------------
// Exact fp32 pred: recompute v2[0,t], a1[0,t] and their dot; compare.
// ---------------------------------------------------------------------------
__global__ __launch_bounds__(256)
void pred_exact(const float* __restrict__ vf, const float* __restrict__ af,
                const float* __restrict__ Wv2, const float* __restrict__ Wa1,
                const float* __restrict__ cs, const float* __restrict__ thrp,
                float* __restrict__ pred)
{
    __shared__ float vs[8][260];
    __shared__ float as_[8][260];
    __shared__ float red[4][8];
    const int t0 = blockIdx.x * 8;
    const int tid = threadIdx.x;
    {
        const int i = tid >> 5, c = (tid & 31) * 8;
        *(float4*)&vs[i][c] = *(const float4*)(vf + (long)(t0 + i) * DD + c);
        *(float4*)&vs[i][c + 4] = *(const float4*)(vf + (long)(t0 + i) * DD + c + 4);
        *(float4*)&as_[i][c] = *(const float4*)(af + (long)(t0 + i) * DD + c);
        *(float4*)&as_[i][c + 4] = *(const float4*)(af + (long)(t0 + i) * DD + c + 4);
    }
    __syncthreads();
    const int j = tid;
    float av[8] = {0.f}, aa[8] = {0.f};
    for (int k = 0; k < DD; k += 4) {
        const float4 wv = *(const float4*)(Wv2 + (long)j * DD + k);
        const float4 wa = *(const float4*)(Wa1 + (long)j * DD + k);
        #pragma unroll
        for (int i = 0; i < 8; ++i) {
            const float4 x = *(const float4*)&vs[i][k];
            av[i] += wv.x * x.x + wv.y * x.y + wv.z * x.z + wv.w * x.w;
            const float4 y = *(const float4*)&as_[i][k];
            aa[i] += wa.x * y.x + wa.y * y.y + wa.z * y.z + wa.w * y.w;
        }
    }
    float p[8];
    #pragma unroll
    for (int i = 0; i < 8; ++i)
        p[i] = fmaxf(av[i], 0.f) * fmaxf(aa[i], 0.f);
    #pragma unroll
    for (int off = 32; off > 0; off >>= 1)
        #pragma unroll
        for (int i = 0; i < 8; ++i) p[i] += __shfl_xor(p[i], off);
    const int lane = tid & 63, wv_ = tid >> 6;
    if (lane == 0)
        #pragma unroll
        for (int i = 0; i < 8; ++i) red[wv_][i] = p[i];
    __syncthreads();
    if (tid < 8) {
        float d = red[0][tid] + red[1][tid] + red[2][tid] + red[3][tid];
        d = fmaxf(d * (1.f / 16.f), 0.f);
        const float thr = thrp[0] * 10.0f / (float)TT;
        pred[t0 + tid] = (d > thr * (cs[t0 + tid] + EPSF)) ? 1.0f : 0.0f;
    }
}

// ---------------------------------------------------------------------------
// Split v_fea/a_fea fp32 -> bf16 h/l pairs. grid.y: 0=v, 1=a.
// ---------------------------------------------------------------------------
__global__ __launch_bounds__(256)
void split_feat(const float* __restrict__ vf, const float* __restrict__ af,
                u16* __restrict__ vfh, u16* __restrict__ vfl,
                u16* __restrict__ afh, u16* __restrict__ afl)
{
    const long i4 = ((long)blockIdx.x * 256 + threadIdx.x) * 4;
    const float* src = blockIdx.y ? af : vf;
    u16* dh = blockIdx.y ? afh : vfh;
    u16* dl = blockIdx.y ? afl : vfl;
    float4 a = *(const float4*)(src + i4);
    ushort4 h4, l4; u16 h;
    h = f2bf(a.x); h4.x = h; l4.x = f2bf(a.x - bf2f(h));
    h = f2bf(a.y); h4.y = h; l4.y = f2bf(a.y - bf2f(h));
    h = f2bf(a.z); h4.z = h; l4.z = f2bf(a.z - bf2f(h));
    h = f2bf(a.w); h4.w = h; l4.w = f2bf(a.w - bf2f(h));
    *(ushort4*)(dh + i4) = h4;
    *(ushort4*)(dl + i4) = l4;
}

// ---------------------------------------------------------------------------
// Split/convert 6 weight matrices into Wsp: [Wv1h Wv1l Wv2h Wv2l Wa1h Wa1l
// Wa2h Wa2l Wvfcb Wafcb], each DD*DD. grid.y = task 0..5.
// ---------------------------------------------------------------------------
__global__ __launch_bounds__(256)
void split_w(const float* __restrict__ w0, const float* __restrict__ w1,
             const float* __restrict__ w2, const float* __restrict__ w3,
             const float* __restrict__ w4, const float* __restrict__ w5,
             u16* __restrict__ out)
{
    const int t = blockIdx.y;
    const float* w = (t == 0) ? w0 : (t == 1) ? w1 : (t == 2) ? w2
                   : (t == 3) ? w3 : (t == 4) ? w4 : w5;
    const int i4 = (blockIdx.x * 256 + threadIdx.x) * 4;
    float4 a = *(const float4*)(w + i4);
    if (t < 4) {
        u16* oh = out + (size_t)t * 2 * DD * DD;
        u16* ol = oh + DD * DD;
        ushort4 h4, l4; u16 h;
        h = f2bf(a.x); h4.x = h; l4.x = f2bf(a.x - bf2f(h));
        h = f2bf(a.y); h4.y = h; l4.y = f2bf(a.y - bf2f(h));
        h = f2bf(a.z); h4.z = h; l4.z = f2bf(a.z - bf2f(h));
        h = f2bf(a.w); h4.w = h; l4.w = f2bf(a.w - bf2f(h));
        *(ushort4*)(oh + i4) = h4;
        *(ushort4*)(ol + i4) = l4;
    } else {
        u16* ob = out + (size_t)8 * DD * DD + (size_t)(t - 4) * DD * DD;
        ushort4 o;
        o.x = f2bf(a.x); o.y = f2bf(a.y); o.z = f2bf(a.z); o.w = f2bf(a.w);
        *(ushort4*)(ob + i4) = o;
    }
}

// ---------------------------------------------------------------------------
// LayerNorm both branches + fuse. 4 rows/block, 1 wave per row. bf16 in,
// fp32 out.
// ---------------------------------------------------------------------------
__global__ __launch_bounds__(256)
void ln_fuse_kernel(const u16* __restrict__ yv, const u16* __restrict__ ya,
                    const float* __restrict__ g, const float* __restrict__ b,
                    float* __restrict__ fuse, float* __restrict__ vpsp,
                    float* __restrict__ apsp)
{
    const long row = (long)blockIdx.x * 4 + (threadIdx.x >> 6);
    const int lane = threadIdx.x & 63;
    const ushort4 hv = *(const ushort4*)(yv + row * DD + lane * 4);
    const ushort4 ha = *(const ushort4*)(ya + row * DD + lane * 4);
    const float xv0 = bf2f(hv.x), xv1 = bf2f(hv.y), xv2 = bf2f(hv.z), xv3 = bf2f(hv.w);
    const float xa0 = bf2f(ha.x), xa1 = bf2f(ha.y), xa2 = bf2f(ha.z), xa3 = bf2f(ha.w);
    float sv = xv0 + xv1 + xv2 + xv3;
    float sa = xa0 + xa1 + xa2 + xa3;
    #pragma unroll
    for (int off = 32; off > 0; off >>= 1) {
        sv += __shfl_xor(sv, off);
        sa += __shfl_xor(sa, off);
    }
    const float mv = sv * (1.f / 256.f);
    const float ma = sa * (1.f / 256.f);
    const float dv0 = xv0 - mv, dv1 = xv1 - mv, dv2 = xv2 - mv, dv3 = xv3 - mv;
    const float da0 = xa0 - ma, da1 = xa1 - ma, da2 = xa2 - ma, da3 = xa3 - ma;
    float qv = dv0 * dv0 + dv1 * dv1 + dv2 * dv2 + dv3 * dv3;
    float qa = da0 * da0 + da1 * da1 + da2 * da2 + da3 * da3;
    #pragma unroll
    for (int off = 32; off > 0; off >>= 1) {
        qv += __shfl_xor(qv, off);
        qa += __shfl_xor(qa, off);
    }
    const float rv = rsqrtf(qv * (1.f / 256.f) + 1e-6f);
    const float ra = rsqrtf(qa * (1.f / 256.f) + 1e-6f);
    const float4 gg = *(const float4*)(g + lane * 4);
    const float4 bb = *(const float4*)(b + lane * 4);
    float4 ov, oa, of;
    ov.x = dv0 * rv * gg.x + bb.x; ov.y = dv1 * rv * gg.y + bb.y;
    ov.z = dv2 * rv * gg.z + bb.z; ov.w = dv3 * rv * gg.w + bb.w;
    oa.x = da0 * ra * gg.x + bb.x; oa.y = da1 * ra * gg.y + bb.y;
    oa.z = da2 * ra * gg.z + bb.z; oa.w = da3 * ra * gg.w + bb.w;
    of.x = 0.5f * (ov.x + oa.x); of.y = 0.5f * (ov.y + oa.y);
    of.z = 0.5f * (ov.z + oa.z); of.w = 0.5f * (ov.w + oa.w);
    *(float4*)(vpsp + row * DD + lane * 4) = ov;
    *(float4*)(apsp + row * DD + lane * 4) = oa;
    *(float4*)(fuse + row * DD + lane * 4) = of;
}

extern "C" void kernel_launch(void* const* d_in, const int* in_sizes, int n_in,
                              void* d_out, int out_size, void* d_ws, size_t ws_size,
                              hipStream_t stream)
{
    const float* a_fea = (const float*)d_in[0];
    const float* v_fea = (const float*)d_in[1];
    const float* thrp  = (const float*)d_in[2];
    const float* Wv1   = (const float*)d_in[3];
    const float* Wv2   = (const float*)d_in[4];
    const float* Wvfc  = (const float*)d_in[5];
    const float* Wa1   = (const float*)d_in[6];
    const float* Wa2   = (const float*)d_in[7];
    const float* Wafc  = (const float*)d_in[8];
    const float* lng   = (const float*)d_in[9];
    const float* lnb   = (const float*)d_in[10];

    const long MT = (long)NBATCH * TT;
    float* out_fuse = (float*)d_out;
    float* out_vpsp = out_fuse + MT * DD;
    float* out_apsp = out_vpsp + MT * DD;
    float* out_pred = out_apsp + MT * DD;

    // ws: v2h v2l a1h a1l yvin yain v1T a2T (8xfb) | rs cs | Wsp(10xDDDD) |
    //     beta(67MB) betaT(67MB). vfh/vfl/afh/afl (transient) alias beta's
    //     front (dead before score writes beta). yvb/yab (fc bf16 out)
    //     alias slots 0-1 (v2h/v2l, dead after score).
    char* ws = (char*)d_ws;
    const size_t fb = (size_t)MT * DD * sizeof(u16);
    const size_t sumB = (size_t)MT * sizeof(float);
    u16* v2h  = (u16*)(ws + 0 * fb);
    u16* v2l  = (u16*)(ws + 1 * fb);
    u16* a1h  = (u16*)(ws + 2 * fb);
    u16* a1l  = (u16*)(ws + 3 * fb);
    u16* yvin = (u16*)(ws + 4 * fb);
    u16* yain = (u16*)(ws + 5 * fb);
    u16* v1T  = (u16*)(ws + 6 * fb);
    u16* a2T  = (u16*)(ws + 7 * fb);
    char* p = ws + 8 * fb;
    float* rs = (float*)(p + 0 * sumB);
    float* cs = (float*)(p + 1 * sumB);
    u16* Wsp  = (u16*)(p + 2 * sumB);
    char* q = p + 2 * sumB + 10 * DD * DD * sizeof(u16);
    const size_t betaB = (size_t)NBATCH * TT * TT * sizeof(u16);   // 67 MB
    u16* beta  = (u16*)q;
    u16* betaT = (u16*)(q + betaB);
    u16* vfh = (u16*)q;            // transient splits, dead before score
    u16* vfl = vfh + MT * DD;
    u16* afh = vfl + MT * DD;
    u16* afl = afh + MT * DD;
    u16* yvb = (u16*)(ws + 0 * fb);        // fc bf16 out, z-stride MT*DD
    u16* yab = yvb + (size_t)MT * DD;

    hipMemsetAsync(rs, 0, 2 * sumB, stream);

    const dim3 blk(256, 1, 1);

    split_feat<<<dim3((unsigned)(MT * DD / 1024), 2, 1), blk, 0, stream>>>(
        v_fea, a_fea, vfh, vfl, afh, afl);
    split_w<<<dim3(DD * DD / 1024, 6, 1), blk, 0, stream>>>(
        Wv1, Wv2, Wa1, Wa2, Wvfc, Wafc, Wsp);

    // 512-thread proj (8 waves), BM=128
    proj_kernel<<<dim3(DD / 64, (unsigned)(MT / 128), 4), dim3(512, 1, 1), 0, stream>>>(
        vfh, vfl, afh, afl, Wsp, v2h, v2l, a1h, a1l, v1T, a2T);

    // 512-thread score (8 waves), natural mapping (R5 verified)
    score_kernel<<<dim3(TT / 128, TT / 128, NBATCH), dim3(512, 1, 1), 0, stream>>>(
        v2h, v2l, a1h, a1l, beta, betaT, rs, cs);
    pred_exact<<<dim3(TT / 8, 1, 1), blk, 0, stream>>>(
        v_fea, a_fea, Wv2, Wa1, cs, thrp, out_pred);

    // grid: x = zz (batch+dir, XCD-affine), y = m0 tile; 512 threads
    pv_kernel<<<dim3(2 * NBATCH, TT / 128, 1), dim3(512, 1, 1), 0, stream>>>(
        beta, betaT, a2T, v1T, rs, cs, thrp, v_fea, a_fea, yvin, yain);

    // 512-thread fc (8 waves)
    fc_kernel<<<dim3(DD / 64, (unsigned)(MT / 128), 2), dim3(512, 1, 1), 0, stream>>>(
        yvin, Wsp + 8 * DD * DD, yvb);
    ln_fuse_kernel<<<dim3((unsigned)(MT / 4), 1, 1), blk, 0, stream>>>(
        yvb, yab, lng, lnb, out_fuse, out_vpsp, out_apsp);
}

// Round 9
// 371.966 us; speedup vs baseline: 1.1444x; 1.0771x over previous
//
#include <hip/hip_runtime.h>
#include <math.h>

#define TT 2048
#define DD 256
#define NBATCH 8
#define EPSF 1e-8f

typedef unsigned short u16;
typedef __attribute__((ext_vector_type(8))) short short8;
typedef __attribute__((ext_vector_type(4))) float f32x4;

__device__ __forceinline__ u16 f2bf(float x) {
    unsigned int u = __builtin_bit_cast(unsigned int, x);
    u += 0x7fffu + ((u >> 16) & 1u);
    return (u16)(u >> 16);
}
__device__ __forceinline__ float bf2f(u16 h) {
    return __builtin_bit_cast(float, (unsigned int)h << 16);
}

// MFMA-fragment LDS index for a [rows x 32k] bf16 tile:
// elem(row,k) -> (((row>>4)*4+(k>>3))*16+(row&15))*8+(k&7)
// Fragment read for 16-row subtile t is ds_read_b128 at (t*64+lane)*8.
__device__ __forceinline__ int frag_dst(int row, int k) {
    return (((row >> 4) * 4 + (k >> 3)) * 16 + (row & 15)) * 8 + (k & 7);
}

// Address-pure bank swizzle (u16 index), applied to both write and read.
__device__ __forceinline__ int swz(int i) { return i ^ ((i >> 2) & 32); }

template<int BR>
__device__ __forceinline__ void stage_tile(const u16* __restrict__ g, u16* s,
                                           int row0, int k0, int ldk, int tid)
{
    #pragma unroll
    for (int i = 0; i < BR / 64; ++i) {
        const int c = tid + 256 * i;
        const int row = c >> 2, q = c & 3;
        *(int4*)(s + swz(frag_dst(row, q * 8))) =
            *(const int4*)(g + (long)(row0 + row) * ldk + k0 + q * 8);
    }
}

// ---------------------------------------------------------------------------
// Combined projections. z = 0:v2(split h/l) 1:a1(split h/l)
//                        2:v1 -> v1T (register-transposed bf16)
//                        3:a2 -> a2T
// 3-term split-bf16 MFMA (rel err ~3e-6). 512 threads = 8 waves (2 wy x
// 4 wx), BM=128, BN=64. Outputs bit-identical to the 256-thread version.
// ---------------------------------------------------------------------------
__global__ __launch_bounds__(512)
void proj_kernel(const u16* __restrict__ vfh, const u16* __restrict__ vfl,
                 const u16* __restrict__ afh, const u16* __restrict__ afl,
                 const u16* __restrict__ Wsp,
                 u16* __restrict__ v2h, u16* __restrict__ v2l,
                 u16* __restrict__ a1h, u16* __restrict__ a1l,
                 u16* __restrict__ v1T, u16* __restrict__ a2T)
{
    const int zz = blockIdx.z;
    const u16* Ah = (zz == 1 || zz == 3) ? afh : vfh;
    const u16* Al = (zz == 1 || zz == 3) ? afl : vfl;
    const int widx = (zz == 0) ? 2 : (zz == 1) ? 4 : (zz == 2) ? 0 : 6;
    const u16* Bh = Wsp + widx * DD * DD;
    const u16* Bl = Bh + DD * DD;
    const bool split = zz < 2;
    u16* Oh = (zz == 0) ? v2h : a1h;
    u16* Ol = (zz == 0) ? v2l : a1l;
    u16* OT = (zz == 2) ? v1T : a2T;

    __shared__ __align__(16) u16 Ah_s[128 * 32], Al_s[128 * 32];
    __shared__ __align__(16) u16 Bh_s[64 * 32], Bl_s[64 * 32];
    const int m0 = blockIdx.y * 128, n0 = blockIdx.x * 64;
    const int tid = threadIdx.x, lane = tid & 63, w = tid >> 6;
    const int wy = w >> 2, wx = w & 3;
    f32x4 acc[4] = {};

    // A staging: all 512 threads, 1 chunk per tile (row tid>>2, q tid&3)
    const int prow = tid >> 2, pq = tid & 3;
    const int dA = swz(frag_dst(prow, pq * 8));
    const u16* gAh = Ah + (long)(m0 + prow) * DD + pq * 8;
    const u16* gAl = Al + (long)(m0 + prow) * DD + pq * 8;
    // B staging: tid<256 -> Bh, tid>=256 -> Bl (row (tid&255)>>2)
    const int brow = (tid & 255) >> 2, bq = tid & 3;
    const int dB = swz(frag_dst(brow, bq * 8));
    const u16* gB = ((tid < 256) ? Bh : Bl) + (long)(n0 + brow) * DD + bq * 8;
    u16* sB = (tid < 256) ? Bh_s : Bl_s;

    int4 rAh = *(const int4*)(gAh);
    int4 rAl = *(const int4*)(gAl);
    int4 rB  = *(const int4*)(gB);

    for (int k0 = 0; k0 < DD; k0 += 32) {
        *(int4*)(Ah_s + dA) = rAh;
        *(int4*)(Al_s + dA) = rAl;
        *(int4*)(sB + dB)   = rB;
        __syncthreads();
        const int kn = (k0 + 32 < DD) ? k0 + 32 : 0;
        rAh = *(const int4*)(gAh + kn);
        rAl = *(const int4*)(gAl + kn);
        rB  = *(const int4*)(gB + kn);
        short8 ah[4], al[4], bh, bl;
        #pragma unroll
        for (int i = 0; i < 4; ++i) {
            ah[i] = *(const short8*)(Ah_s + swz(((wy * 4 + i) * 64 + lane) * 8));
            al[i] = *(const short8*)(Al_s + swz(((wy * 4 + i) * 64 + lane) * 8));
        }
        bh = *(const short8*)(Bh_s + swz((wx * 64 + lane) * 8));
        bl = *(const short8*)(Bl_s + swz((wx * 64 + lane) * 8));
        #pragma unroll
        for (int i = 0; i < 4; ++i) {
            acc[i] = __builtin_amdgcn_mfma_f32_16x16x32_bf16(ah[i], bl, acc[i], 0, 0, 0);
            acc[i] = __builtin_amdgcn_mfma_f32_16x16x32_bf16(al[i], bh, acc[i], 0, 0, 0);
            acc[i] = __builtin_amdgcn_mfma_f32_16x16x32_bf16(ah[i], bh, acc[i], 0, 0, 0);
        }
        __syncthreads();
    }
    const int quad = lane >> 4, col = lane & 15;
    const int c = n0 + wx * 16 + col;
    #pragma unroll
    for (int i = 0; i < 4; ++i) {
        const int rbase = m0 + wy * 64 + i * 16 + quad * 4;
        if (split) {
            #pragma unroll
            for (int r = 0; r < 4; ++r) {
                const float v = fmaxf(acc[i][r], 0.f);
                const u16 h = f2bf(v);
                Oh[(long)(rbase + r) * DD + c] = h;
                Ol[(long)(rbase + r) * DD + c] = f2bf(v - bf2f(h));
            }
        } else {
            // transposed: OT[b][d=c][t]; 4 consecutive t = one b64 store
            short4 pk;
            pk.x = (short)f2bf(fmaxf(acc[i][0], 0.f));
            pk.y = (short)f2bf(fmaxf(acc[i][1], 0.f));
            pk.z = (short)f2bf(fmaxf(acc[i][2], 0.f));
            pk.w = (short)f2bf(fmaxf(acc[i][3], 0.f));
            const int b = rbase >> 11, t = rbase & (TT - 1);
            *(short4*)(OT + ((long)b * DD + c) * TT + t) = pk;
        }
    }
}

// ---------------------------------------------------------------------------
// Scores: beta(bf16) = relu(v2.a1/16), 3-term split MFMA. BM=BN=128.
// 512 threads = 8 waves (2 wy x 4 wx). 2-DEEP register-prefetch rotation:
// two prefetch sets alternate; each set's loads are issued 2 K-steps
// before consumption (window spans a full step + MFMA phase, vs 1 MFMA
// phase at 1-deep). s_barrier does not drain loads-to-VGPR, so the
// window crosses barriers for free. Numerics identical to R5/R8.
// ---------------------------------------------------------------------------
__global__ __launch_bounds__(512)
void score_kernel(const u16* __restrict__ v2h, const u16* __restrict__ v2l,
                  const u16* __restrict__ a1h, const u16* __restrict__ a1l,
                  u16* __restrict__ beta, u16* __restrict__ betaT,
                  float* __restrict__ rs, float* __restrict__ cs)
{
    // S serves as: 4 staging tiles (32 KB) in the K-loop, then the 128x128
    // store buffer (stride 136, 34 KB) in the epilogue.
    __shared__ __align__(16) u16 S[128 * 136];
    u16* Ah_s = S;
    u16* Al_s = S + 4096;
    u16* Bh_s = S + 8192;
    u16* Bl_s = S + 12288;
    const int z = blockIdx.z;
    const int m0 = blockIdx.y * 128, n0 = blockIdx.x * 128;
    const int tid = threadIdx.x, lane = tid & 63, w = tid >> 6;
    const int wy = w >> 2, wx = w & 3;              // 2 x 4 waves
    const long zoff = (long)z * TT * DD;
    f32x4 acc[4][2] = {};

    // staging: 512 threads, one 16B chunk per tile per thread
    const int prow = tid >> 2, pq = tid & 3;        // row 0..127, k-chunk 0..3
    const int d0 = swz(frag_dst(prow, pq * 8));
    const u16* gAh = v2h + zoff + (long)(m0 + prow) * DD + pq * 8;
    const u16* gAl = v2l + zoff + (long)(m0 + prow) * DD + pq * 8;
    const u16* gBh = a1h + zoff + (long)(n0 + prow) * DD + pq * 8;
    const u16* gBl = a1l + zoff + (long)(n0 + prow) * DD + pq * 8;

    // 2-deep prologue: set0 <- k=0, set1 <- k=32
    int4 rA0h = *(const int4*)(gAh),      rA0l = *(const int4*)(gAl);
    int4 rB0h = *(const int4*)(gBh),      rB0l = *(const int4*)(gBl);
    int4 rA1h = *(const int4*)(gAh + 32), rA1l = *(const int4*)(gAl + 32);
    int4 rB1h = *(const int4*)(gBh + 32), rB1l = *(const int4*)(gBl + 32);

    auto kstep = [&](int4& vAh, int4& vAl, int4& vBh, int4& vBl, int kfut) {
        *(int4*)(Ah_s + d0) = vAh;
        *(int4*)(Al_s + d0) = vAl;
        *(int4*)(Bh_s + d0) = vBh;
        *(int4*)(Bl_s + d0) = vBl;
        __syncthreads();
        // refill this set for its next turn (2 steps ahead)
        vAh = *(const int4*)(gAh + kfut);
        vAl = *(const int4*)(gAl + kfut);
        vBh = *(const int4*)(gBh + kfut);
        vBl = *(const int4*)(gBl + kfut);
        short8 ah[4], al[4], bh[2], bl[2];
        #pragma unroll
        for (int i = 0; i < 4; ++i) {
            ah[i] = *(const short8*)(Ah_s + swz(((wy * 4 + i) * 64 + lane) * 8));
            al[i] = *(const short8*)(Al_s + swz(((wy * 4 + i) * 64 + lane) * 8));
        }
        #pragma unroll
        for (int j = 0; j < 2; ++j) {
            bh[j] = *(const short8*)(Bh_s + swz(((wx * 2 + j) * 64 + lane) * 8));
            bl[j] = *(const short8*)(Bl_s + swz(((wx * 2 + j) * 64 + lane) * 8));
        }
        #pragma unroll
        for (int i = 0; i < 4; ++i)
            #pragma unroll
            for (int j = 0; j < 2; ++j) {
                acc[i][j] = __builtin_amdgcn_mfma_f32_16x16x32_bf16(ah[i], bl[j], acc[i][j], 0, 0, 0);
                acc[i][j] = __builtin_amdgcn_mfma_f32_16x16x32_bf16(al[i], bh[j], acc[i][j], 0, 0, 0);
                acc[i][j] = __builtin_amdgcn_mfma_f32_16x16x32_bf16(ah[i], bh[j], acc[i][j], 0, 0, 0);
            }
        __syncthreads();
    };
    // 8 K-steps, fully unrolled; dead refills (past K) reload k=0 harmlessly
    kstep(rA0h, rA0l, rB0h, rB0l, 64);
    kstep(rA1h, rA1l, rB1h, rB1l, 96);
    kstep(rA0h, rA0l, rB0h, rB0l, 128);
    kstep(rA1h, rA1l, rB1h, rB1l, 160);
    kstep(rA0h, rA0l, rB0h, rB0l, 192);
    kstep(rA1h, rA1l, rB1h, rB1l, 224);
    kstep(rA0h, rA0l, rB0h, rB0l, 0);
    kstep(rA1h, rA1l, rB1h, rB1l, 0);

    const int quad = lane >> 4, col = lane & 15;
    const float scale = 1.f / 16.f;
    #pragma unroll
    for (int i = 0; i < 4; ++i)
        #pragma unroll
        for (int j = 0; j < 2; ++j)
            #pragma unroll
            for (int r = 0; r < 4; ++r)
                acc[i][j][r] = fmaxf(acc[i][j][r] * scale, 0.f);

    // beta row-major: stage into S[rl][cl] (stride 136), coalesced int4 out
    #pragma unroll
    for (int i = 0; i < 4; ++i) {
        const int rl = (wy * 4 + i) * 16 + quad * 4;
        #pragma unroll
        for (int j = 0; j < 2; ++j) {
            const int cl = (wx * 2 + j) * 16 + col;
            #pragma unroll
            for (int r = 0; r < 4; ++r)
                S[(rl + r) * 136 + cl] = f2bf(acc[i][j][r]);
        }
    }
    __syncthreads();
    #pragma unroll
    for (int it = 0; it < 4; ++it) {
        const int idx = tid + 512 * it;
        const int rl = idx >> 4, cq = idx & 15;
        const int4 v = *(const int4*)(S + rl * 136 + cq * 8);
        *(int4*)(beta + ((long)z * TT + m0 + rl) * TT + n0 + cq * 8) = v;
    }
    // row sums (fp32-exact atomics): wave partial = its 32 cols
    #pragma unroll
    for (int i = 0; i < 4; ++i)
        #pragma unroll
        for (int r = 0; r < 4; ++r) {
            float rp = acc[i][0][r] + acc[i][1][r];
            rp += __shfl_xor(rp, 1); rp += __shfl_xor(rp, 2);
            rp += __shfl_xor(rp, 4); rp += __shfl_xor(rp, 8);
            if (col == 0) {
                const int row = m0 + (wy * 4 + i) * 16 + quad * 4 + r;
                atomicAdd(&rs[(long)z * TT + row], rp);
            }
        }
    // col sums: wave partial = its 64 rows
    #pragma unroll
    for (int j = 0; j < 2; ++j) {
        float cp = 0.f;
        #pragma unroll
        for (int i = 0; i < 4; ++i)
            #pragma unroll
            for (int r = 0; r < 4; ++r) cp += acc[i][j][r];
        cp += __shfl_xor(cp, 16); cp += __shfl_xor(cp, 32);
        if (lane < 16) {
            const int c = n0 + (wx * 2 + j) * 16 + col;
            atomicAdd(&cs[(long)z * TT + c], cp);
        }
    }
    // betaT via LDS transpose: S[cl][rl] (stride 136), coalesced int4 out
    __syncthreads();
    #pragma unroll
    for (int i = 0; i < 4; ++i)
        #pragma unroll
        for (int j = 0; j < 2; ++j) {
            const int cl = (wx * 2 + j) * 16 + col;
            const int rl = (wy * 4 + i) * 16 + quad * 4;
            short4 pk;
            pk.x = (short)f2bf(acc[i][j][0]);
            pk.y = (short)f2bf(acc[i][j][1]);
            pk.z = (short)f2bf(acc[i][j][2]);
            pk.w = (short)f2bf(acc[i][j][3]);
            *(short4*)(S + cl * 136 + rl) = pk;
        }
    __syncthreads();
    #pragma unroll
    for (int it = 0; it < 4; ++it) {
        const int idx = tid + 512 * it;
        const int cl = idx >> 4, tq = idx & 15;
        const int4 v = *(const int4*)(S + cl * 136 + tq * 8);
        *(int4*)(betaT + ((long)z * TT + n0 + cl) * TT + m0 + tq * 8) = v;
    }
}

// ---------------------------------------------------------------------------
// Unified PV, full-D tile. zz<8: v-attends-a (P=beta, sums=rs, V=a2T,
// resid=v_fea); zz>=8: a-attends-v (P=betaT, sums=cs, V=v1T, resid=a_fea).
// BM=128, BN=256(=D), K=TT. 512 threads = 8 waves (2x4). 2-deep prefetch
// rotation (same scheme as score; threshold/rpart semantics unchanged).
// ---------------------------------------------------------------------------
__global__ __launch_bounds__(512)
void pv_kernel(const u16* __restrict__ beta, const u16* __restrict__ betaT,
               const u16* __restrict__ a2T, const u16* __restrict__ v1T,
               const float* __restrict__ rs, const float* __restrict__ cs,
               const float* __restrict__ thrp,
               const float* __restrict__ v_fea, const float* __restrict__ a_fea,
               u16* __restrict__ yvin, u16* __restrict__ yain)
{
    __shared__ __align__(16) u16 A_s[128 * 32], B_s[256 * 32];
    __shared__ float sthr[128], sA[128], ssum[128];
    const int zz = blockIdx.x;
    const int m0 = blockIdx.y * 128;
    const int z = zz & 7;
    const bool av = zz >= 8;
    const u16* P      = av ? betaT : beta;
    const u16* VT     = av ? v1T : a2T;
    const float* sums = av ? cs : rs;
    const float* resid = av ? a_fea : v_fea;
    u16* outb         = av ? yain : yvin;

    const int tid = threadIdx.x, lane = tid & 63, w = tid >> 6;
    const int wy = w >> 2, wx = w & 3;
    const float thr = thrp[0] * 10.0f / (float)TT;
    if (tid < 128) {
        const float s = sums[(long)z * TT + m0 + tid];
        sA[tid] = s; sthr[tid] = thr * (s + EPSF); ssum[tid] = 0.f;
    }
    __syncthreads();
    f32x4 acc[4][4] = {};
    float rpart = 0.f;
    const int arow = tid >> 2, aq = tid & 3;          // A: 128 rows x 4 chunks
    const u16* Pp = P + ((long)z * TT + m0 + arow) * TT + aq * 8;
    const u16* V0 = VT + (long)z * DD * TT + (long)arow * TT + aq * 8;
    const u16* V1 = V0 + (long)128 * TT;
    const int da  = swz(frag_dst(arow, aq * 8));
    const int db1 = swz(frag_dst(arow + 128, aq * 8));
    const float ct = thr; // placeholder (per-row threshold read in step)

    // 2-deep prologue: set0 <- k=0, set1 <- k=32
    int4 Ar0  = *(const int4*)(Pp);      int4 Ar1  = *(const int4*)(Pp + 32);
    int4 Br00 = *(const int4*)(V0);      int4 Br01 = *(const int4*)(V0 + 32);
    int4 Br10 = *(const int4*)(V1);      int4 Br11 = *(const int4*)(V1 + 32);

    auto pvstep = [&](int4& vA, int4& vB0, int4& vB1, int kfut) {
        union { int4 v; u16 us[8]; } U;
        U.v = vA;
        const float cthr = sthr[arow];
        float ss = 0.f;
        #pragma unroll
        for (int t = 0; t < 8; ++t) {
            const float v = bf2f(U.us[t]);
            if (v > cthr) ss += v; else U.us[t] = 0;
        }
        rpart += ss;
        *(int4*)(A_s + da) = U.v;
        *(int4*)(B_s + da) = vB0;
        *(int4*)(B_s + db1) = vB1;
        __syncthreads();
        // refill this set for its next turn (2 steps ahead)
        vA  = *(const int4*)(Pp + kfut);
        vB0 = *(const int4*)(V0 + kfut);
        vB1 = *(const int4*)(V1 + kfut);
        short8 a[4], b[4];
        #pragma unroll
        for (int i = 0; i < 4; ++i)
            a[i] = *(const short8*)(A_s + swz(((wy * 4 + i) * 64 + lane) * 8));
        #pragma unroll
        for (int j = 0; j < 4; ++j)
            b[j] = *(const short8*)(B_s + swz(((wx * 4 + j) * 64 + lane) * 8));
        #pragma unroll
        for (int i = 0; i < 4; ++i)
            #pragma unroll
            for (int j = 0; j < 4; ++j)
                acc[i][j] = __builtin_amdgcn_mfma_f32_16x16x32_bf16(a[i], b[j], acc[i][j], 0, 0, 0);
        __syncthreads();
    };
    (void)ct;
    for (int k0 = 0; k0 < TT; k0 += 64) {
        pvstep(Ar0, Br00, Br10, (k0 + 64 < TT) ? k0 + 64 : 0);
        pvstep(Ar1, Br01, Br11, (k0 + 96 < TT) ? k0 + 96 : 0);
    }
    atomicAdd(&ssum[arow], rpart);
    __syncthreads();

    const int quad = lane >> 4, col = lane & 15;
    #pragma unroll
    for (int i = 0; i < 4; ++i)
        #pragma unroll
        for (int j = 0; j < 4; ++j) {
            const int c = (wx * 4 + j) * 16 + col;
            #pragma unroll
            for (int r = 0; r < 4; ++r) {
                const int lrow = (wy * 4 + i) * 16 + quad * 4 + r;
                const int row = m0 + lrow;
                const float inv = 1.0f / (ssum[lrow] + EPSF * (sA[lrow] + EPSF));
                const float v = acc[i][j][r] * inv + resid[((long)z * TT + row) * DD + c];
                outb[((long)z * TT + row) * DD + c] = f2bf(v);
            }
        }
}

// ---------------------------------------------------------------------------
// FC: y = relu(yin @ Wfc^T), bf16 out. 512 threads = 8 waves (2 wy x 4 wx),
// BM=128, BN=64. z selects branch via fixed strides.
// ---------------------------------------------------------------------------
__global__ __launch_bounds__(512)
void fc_kernel(const u16* __restrict__ Ain, const u16* __restrict__ Wb,
               u16* __restrict__ Cb)
{
    const int z = blockIdx.z;
    const u16* A = Ain + (size_t)z * (size_t)NBATCH * TT * DD;
    const u16* B = Wb + (size_t)z * DD * DD;
    u16* C = Cb + (size_t)z * (size_t)NBATCH * TT * DD;
    __shared__ __align__(16) u16 A_s[128 * 32], B_s[64 * 32];
    const int m0 = blockIdx.y * 128, n0 = blockIdx.x * 64;
    const int tid = threadIdx.x, lane = tid & 63, w = tid >> 6;
    const int wy = w >> 2, wx = w & 3;
    f32x4 acc[4] = {};

    const int prow = tid >> 2, pq = tid & 3;
    const int dA = swz(frag_dst(prow, pq * 8));
    const u16* gA = A + (long)(m0 + prow) * DD + pq * 8;
    const int brow = (tid & 255) >> 2, bq = tid & 3;
    const int dB = swz(frag_dst(brow, bq * 8));
    const u16* gB = B + (long)(n0 + brow) * DD + bq * 8;

    int4 rA = *(const int4*)(gA);
    int4 rB = *(const int4*)(gB);

    for (int k0 = 0; k0 < DD; k0 += 32) {
        *(int4*)(A_s + dA) = rA;
        if (tid < 256) *(int4*)(B_s + dB) = rB;
        __syncthreads();
        const int kn = (k0 + 32 < DD) ? k0 + 32 : 0;
        rA = *(const int4*)(gA + kn);
        rB = *(const int4*)(gB + kn);
        short8 a[4], b;
        #pragma unroll
        for (int i = 0; i < 4; ++i)
            a[i] = *(const short8*)(A_s + swz(((wy * 4 + i) * 64 + lane) * 8));
        b = *(const short8*)(B_s + swz((wx * 64 + lane) * 8));
        #pragma unroll
        for (int i = 0; i < 4; ++i)
            acc[i] = __builtin_amdgcn_mfma_f32_16x16x32_bf16(a[i], b, acc[i], 0, 0, 0);
        __syncthreads();
    }
    const int quad = lane >> 4, col = lane & 15;
    const int c = n0 + wx * 16 + col;
    #pragma unroll
    for (int i = 0; i < 4; ++i) {
        #pragma unroll
        for (int r = 0; r < 4; ++r) {
            const int row = m0 + wy * 64 + i * 16 + quad * 4 + r;
            C[(long)row * DD + c] = f2bf(fmaxf(acc[i][r], 0.f));
        }
    }
}

// ---------------------------------------------------------------------------
// Exact fp32 pred: recompute v2[0,t], a1[0,t] and their dot; compare.
// ---------------------------------------------------------------------------
__global__ __launch_bounds__(256)
void pred_exact(const float* __restrict__ vf, const float* __restrict__ af,
                const float* __restrict__ Wv2, const float* __restrict__ Wa1,
                const float* __restrict__ cs, const float* __restrict__ thrp,
                float* __restrict__ pred)
{
    __shared__ float vs[8][260];
    __shared__ float as_[8][260];
    __shared__ float red[4][8];
    const int t0 = blockIdx.x * 8;
    const int tid = threadIdx.x;
    {
        const int i = tid >> 5, c = (tid & 31) * 8;
        *(float4*)&vs[i][c] = *(const float4*)(vf + (long)(t0 + i) * DD + c);
        *(float4*)&vs[i][c + 4] = *(const float4*)(vf + (long)(t0 + i) * DD + c + 4);
        *(float4*)&as_[i][c] = *(const float4*)(af + (long)(t0 + i) * DD + c);
        *(float4*)&as_[i][c + 4] = *(const float4*)(af + (long)(t0 + i) * DD + c + 4);
    }
    __syncthreads();
    const int j = tid;
    float av[8] = {0.f}, aa[8] = {0.f};
    for (int k = 0; k < DD; k += 4) {
        const float4 wv = *(const float4*)(Wv2 + (long)j * DD + k);
        const float4 wa = *(const float4*)(Wa1 + (long)j * DD + k);
        #pragma unroll
        for (int i = 0; i < 8; ++i) {
            const float4 x = *(const float4*)&vs[i][k];
            av[i] += wv.x * x.x + wv.y * x.y + wv.z * x.z + wv.w * x.w;
            const float4 y = *(const float4*)&as_[i][k];
            aa[i] += wa.x * y.x + wa.y * y.y + wa.z * y.z + wa.w * y.w;
        }
    }
    float p[8];
    #pragma unroll
    for (int i = 0; i < 8; ++i)
        p[i] = fmaxf(av[i], 0.f) * fmaxf(aa[i], 0.f);
    #pragma unroll
    for (int off = 32; off > 0; off >>= 1)
        #pragma unroll
        for (int i = 0; i < 8; ++i) p[i] += __shfl_xor(p[i], off);
    const int lane = tid & 63, wv_ = tid >> 6;
    if (lane == 0)
        #pragma unroll
        for (int i = 0; i < 8; ++i) red[wv_][i] = p[i];
    __syncthreads();
    if (tid < 8) {
        float d = red[0][tid] + red[1][tid] + red[2][tid] + red[3][tid];
        d = fmaxf(d * (1.f / 16.f), 0.f);
        const float thr = thrp[0] * 10.0f / (float)TT;
        pred[t0 + tid] = (d > thr * (cs[t0 + tid] + EPSF)) ? 1.0f : 0.0f;
    }
}

// ---------------------------------------------------------------------------
// Split v_fea/a_fea fp32 -> bf16 h/l pairs. grid.y: 0=v, 1=a.
// ---------------------------------------------------------------------------
__global__ __launch_bounds__(256)
void split_feat(const float* __restrict__ vf, const float* __restrict__ af,
                u16* __restrict__ vfh, u16* __restrict__ vfl,
                u16* __restrict__ afh, u16* __restrict__ afl)
{
    const long i4 = ((long)blockIdx.x * 256 + threadIdx.x) * 4;
    const float* src = blockIdx.y ? af : vf;
    u16* dh = blockIdx.y ? afh : vfh;
    u16* dl = blockIdx.y ? afl : vfl;
    float4 a = *(const float4*)(src + i4);
    ushort4 h4, l4; u16 h;
    h = f2bf(a.x); h4.x = h; l4.x = f2bf(a.x - bf2f(h));
    h = f2bf(a.y); h4.y = h; l4.y = f2bf(a.y - bf2f(h));
    h = f2bf(a.z); h4.z = h; l4.z = f2bf(a.z - bf2f(h));
    h = f2bf(a.w); h4.w = h; l4.w = f2bf(a.w - bf2f(h));
    *(ushort4*)(dh + i4) = h4;
    *(ushort4*)(dl + i4) = l4;
}

// ---------------------------------------------------------------------------
// Split/convert 6 weight matrices into Wsp: [Wv1h Wv1l Wv2h Wv2l Wa1h Wa1l
// Wa2h Wa2l Wvfcb Wafcb], each DD*DD. grid.y = task 0..5.
// ---------------------------------------------------------------------------
__global__ __launch_bounds__(256)
void split_w(const float* __restrict__ w0, const float* __restrict__ w1,
             const float* __restrict__ w2, const float* __restrict__ w3,
             const float* __restrict__ w4, const float* __restrict__ w5,
             u16* __restrict__ out)
{
    const int t = blockIdx.y;
    const float* w = (t == 0) ? w0 : (t == 1) ? w1 : (t == 2) ? w2
                   : (t == 3) ? w3 : (t == 4) ? w4 : w5;
    const int i4 = (blockIdx.x * 256 + threadIdx.x) * 4;
    float4 a = *(const float4*)(w + i4);
    if (t < 4) {
        u16* oh = out + (size_t)t * 2 * DD * DD;
        u16* ol = oh + DD * DD;
        ushort4 h4, l4; u16 h;
        h = f2bf(a.x); h4.x = h; l4.x = f2bf(a.x - bf2f(h));
        h = f2bf(a.y); h4.y = h; l4.y = f2bf(a.y - bf2f(h));
        h = f2bf(a.z); h4.z = h; l4.z = f2bf(a.z - bf2f(h));
        h = f2bf(a.w); h4.w = h; l4.w = f2bf(a.w - bf2f(h));
        *(ushort4*)(oh + i4) = h4;
        *(ushort4*)(ol + i4) = l4;
    } else {
        u16* ob = out + (size_t)8 * DD * DD + (size_t)(t - 4) * DD * DD;
        ushort4 o;
        o.x = f2bf(a.x); o.y = f2bf(a.y); o.z = f2bf(a.z); o.w = f2bf(a.w);
        *(ushort4*)(ob + i4) = o;
    }
}

// ---------------------------------------------------------------------------
// LayerNorm both branches + fuse. 4 rows/block, 1 wave per row. bf16 in,
// fp32 out.
// ---------------------------------------------------------------------------
__global__ __launch_bounds__(256)
void ln_fuse_kernel(const u16* __restrict__ yv, const u16* __restrict__ ya,
                    const float* __restrict__ g, const float* __restrict__ b,
                    float* __restrict__ fuse, float* __restrict__ vpsp,
                    float* __restrict__ apsp)
{
    const long row = (long)blockIdx.x * 4 + (threadIdx.x >> 6);
    const int lane = threadIdx.x & 63;
    const ushort4 hv = *(const ushort4*)(yv + row * DD + lane * 4);
    const ushort4 ha = *(const ushort4*)(ya + row * DD + lane * 4);
    const float xv0 = bf2f(hv.x), xv1 = bf2f(hv.y), xv2 = bf2f(hv.z), xv3 = bf2f(hv.w);
    const float xa0 = bf2f(ha.x), xa1 = bf2f(ha.y), xa2 = bf2f(ha.z), xa3 = bf2f(ha.w);
    float sv = xv0 + xv1 + xv2 + xv3;
    float sa = xa0 + xa1 + xa2 + xa3;
    #pragma unroll
    for (int off = 32; off > 0; off >>= 1) {
        sv += __shfl_xor(sv, off);
        sa += __shfl_xor(sa, off);
    }
    const float mv = sv * (1.f / 256.f);
    const float ma = sa * (1.f / 256.f);
    const float dv0 = xv0 - mv, dv1 = xv1 - mv, dv2 = xv2 - mv, dv3 = xv3 - mv;
    const float da0 = xa0 - ma, da1 = xa1 - ma, da2 = xa2 - ma, da3 = xa3 - ma;
    float qv = dv0 * dv0 + dv1 * dv1 + dv2 * dv2 + dv3 * dv3;
    float qa = da0 * da0 + da1 * da1 + da2 * da2 + da3 * da3;
    #pragma unroll
    for (int off = 32; off > 0; off >>= 1) {
        qv += __shfl_xor(qv, off);
        qa += __shfl_xor(qa, off);
    }
    const float rv = rsqrtf(qv * (1.f / 256.f) + 1e-6f);
    const float ra = rsqrtf(qa * (1.f / 256.f) + 1e-6f);
    const float4 gg = *(const float4*)(g + lane * 4);
    const float4 bb = *(const float4*)(b + lane * 4);
    float4 ov, oa, of;
    ov.x = dv0 * rv * gg.x + bb.x; ov.y = dv1 * rv * gg.y + bb.y;
    ov.z = dv2 * rv * gg.z + bb.z; ov.w = dv3 * rv * gg.w + bb.w;
    oa.x = da0 * ra * gg.x + bb.x; oa.y = da1 * ra * gg.y + bb.y;
    oa.z = da2 * ra * gg.z + bb.z; oa.w = da3 * ra * gg.w + bb.w;
    of.x = 0.5f * (ov.x + oa.x); of.y = 0.5f * (ov.y + oa.y);
    of.z = 0.5f * (ov.z + oa.z); of.w = 0.5f * (ov.w + oa.w);
    *(float4*)(vpsp + row * DD + lane * 4) = ov;
    *(float4*)(apsp + row * DD + lane * 4) = oa;
    *(float4*)(fuse + row * DD + lane * 4) = of;
}

extern "C" void kernel_launch(void* const* d_in, const int* in_sizes, int n_in,
                              void* d_out, int out_size, void* d_ws, size_t ws_size,
                              hipStream_t stream)
{
    const float* a_fea = (const float*)d_in[0];
    const float* v_fea = (const float*)d_in[1];
    const float* thrp  = (const float*)d_in[2];
    const float* Wv1   = (const float*)d_in[3];
    const float* Wv2   = (const float*)d_in[4];
    const float* Wvfc  = (const float*)d_in[5];
    const float* Wa1   = (const float*)d_in[6];
    const float* Wa2   = (const float*)d_in[7];
    const float* Wafc  = (const float*)d_in[8];
    const float* lng   = (const float*)d_in[9];
    const float* lnb   = (const float*)d_in[10];

    const long MT = (long)NBATCH * TT;
    float* out_fuse = (float*)d_out;
    float* out_vpsp = out_fuse + MT * DD;
    float* out_apsp = out_vpsp + MT * DD;
    float* out_pred = out_apsp + MT * DD;

    // ws: v2h v2l a1h a1l yvin yain v1T a2T (8xfb) | rs cs | Wsp(10xDDDD) |
    //     beta(67MB) betaT(67MB). vfh/vfl/afh/afl (transient) alias beta's
    //     front (dead before score writes beta). yvb/yab (fc bf16 out)
    //     alias slots 0-1 (v2h/v2l, dead after score).
    char* ws = (char*)d_ws;
    const size_t fb = (size_t)MT * DD * sizeof(u16);
    const size_t sumB = (size_t)MT * sizeof(float);
    u16* v2h  = (u16*)(ws + 0 * fb);
    u16* v2l  = (u16*)(ws + 1 * fb);
    u16* a1h  = (u16*)(ws + 2 * fb);
    u16* a1l  = (u16*)(ws + 3 * fb);
    u16* yvin = (u16*)(ws + 4 * fb);
    u16* yain = (u16*)(ws + 5 * fb);
    u16* v1T  = (u16*)(ws + 6 * fb);
    u16* a2T  = (u16*)(ws + 7 * fb);
    char* p = ws + 8 * fb;
    float* rs = (float*)(p + 0 * sumB);
    float* cs = (float*)(p + 1 * sumB);
    u16* Wsp  = (u16*)(p + 2 * sumB);
    char* q = p + 2 * sumB + 10 * DD * DD * sizeof(u16);
    const size_t betaB = (size_t)NBATCH * TT * TT * sizeof(u16);   // 67 MB
    u16* beta  = (u16*)q;
    u16* betaT = (u16*)(q + betaB);
    u16* vfh = (u16*)q;            // transient splits, dead before score
    u16* vfl = vfh + MT * DD;
    u16* afh = vfl + MT * DD;
    u16* afl = afh + MT * DD;
    u16* yvb = (u16*)(ws + 0 * fb);        // fc bf16 out, z-stride MT*DD
    u16* yab = yvb + (size_t)MT * DD;

    hipMemsetAsync(rs, 0, 2 * sumB, stream);

    const dim3 blk(256, 1, 1);

    split_feat<<<dim3((unsigned)(MT * DD / 1024), 2, 1), blk, 0, stream>>>(
        v_fea, a_fea, vfh, vfl, afh, afl);
    split_w<<<dim3(DD * DD / 1024, 6, 1), blk, 0, stream>>>(
        Wv1, Wv2, Wa1, Wa2, Wvfc, Wafc, Wsp);

    // 512-thread proj (8 waves), BM=128
    proj_kernel<<<dim3(DD / 64, (unsigned)(MT / 128), 4), dim3(512, 1, 1), 0, stream>>>(
        vfh, vfl, afh, afl, Wsp, v2h, v2l, a1h, a1l, v1T, a2T);

    // 512-thread score (8 waves), 2-deep prefetch, natural mapping
    score_kernel<<<dim3(TT / 128, TT / 128, NBATCH), dim3(512, 1, 1), 0, stream>>>(
        v2h, v2l, a1h, a1l, beta, betaT, rs, cs);
    pred_exact<<<dim3(TT / 8, 1, 1), blk, 0, stream>>>(
        v_fea, a_fea, Wv2, Wa1, cs, thrp, out_pred);

    // grid: x = zz (batch+dir, XCD-affine), y = m0 tile; 512 threads
    pv_kernel<<<dim3(2 * NBATCH, TT / 128, 1), dim3(512, 1, 1), 0, stream>>>(
        beta, betaT, a2T, v1T, rs, cs, thrp, v_fea, a_fea, yvin, yain);

    // 512-thread fc (8 waves)
    fc_kernel<<<dim3(DD / 64, (unsigned)(MT / 128), 2), dim3(512, 1, 1), 0, stream>>>(
        yvin, Wsp + 8 * DD * DD, yvb);
    ln_fuse_kernel<<<dim3((unsigned)(MT / 4), 1, 1), blk, 0, stream>>>(
        yvb, yab, lng, lnb, out_fuse, out_vpsp, out_apsp);
}

// Round 10
// 371.432 us; speedup vs baseline: 1.1461x; 1.0014x over previous
//
#include <hip/hip_runtime.h>
#include <math.h>

#define TT 2048
#define DD 256
#define NBATCH 8
#define EPSF 1e-8f

typedef unsigned short u16;
typedef __attribute__((ext_vector_type(8))) short short8;
typedef __attribute__((ext_vector_type(4))) float f32x4;

__device__ __forceinline__ u16 f2bf(float x) {
    unsigned int u = __builtin_bit_cast(unsigned int, x);
    u += 0x7fffu + ((u >> 16) & 1u);
    return (u16)(u >> 16);
}
__device__ __forceinline__ float bf2f(u16 h) {
    return __builtin_bit_cast(float, (unsigned int)h << 16);
}

// MFMA-fragment LDS index for a [rows x 32k] bf16 tile:
// elem(row,k) -> (((row>>4)*4+(k>>3))*16+(row&15))*8+(k&7)
// Fragment read for 16-row subtile t is ds_read_b128 at (t*64+lane)*8.
__device__ __forceinline__ int frag_dst(int row, int k) {
    return (((row >> 4) * 4 + (k >> 3)) * 16 + (row & 15)) * 8 + (k & 7);
}

// Address-pure bank swizzle (u16 index), applied to both write and read.
__device__ __forceinline__ int swz(int i) { return i ^ ((i >> 2) & 32); }

template<int BR>
__device__ __forceinline__ void stage_tile(const u16* __restrict__ g, u16* s,
                                           int row0, int k0, int ldk, int tid)
{
    #pragma unroll
    for (int i = 0; i < BR / 64; ++i) {
        const int c = tid + 256 * i;
        const int row = c >> 2, q = c & 3;
        *(int4*)(s + swz(frag_dst(row, q * 8))) =
            *(const int4*)(g + (long)(row0 + row) * ldk + k0 + q * 8);
    }
}

// ---------------------------------------------------------------------------
// Combined projections. z = 0:v2(split h/l) 1:a1(split h/l)
//                        2:v1 -> v1T (register-transposed bf16)
//                        3:a2 -> a2T
// 3-term split-bf16 MFMA (rel err ~3e-6). 512 threads = 8 waves (2 wy x
// 4 wx), BM=128, BN=64. Outputs bit-identical to the 256-thread version.
// ---------------------------------------------------------------------------
__global__ __launch_bounds__(512)
void proj_kernel(const u16* __restrict__ vfh, const u16* __restrict__ vfl,
                 const u16* __restrict__ afh, const u16* __restrict__ afl,
                 const u16* __restrict__ Wsp,
                 u16* __restrict__ v2h, u16* __restrict__ v2l,
                 u16* __restrict__ a1h, u16* __restrict__ a1l,
                 u16* __restrict__ v1T, u16* __restrict__ a2T)
{
    const int zz = blockIdx.z;
    const u16* Ah = (zz == 1 || zz == 3) ? afh : vfh;
    const u16* Al = (zz == 1 || zz == 3) ? afl : vfl;
    const int widx = (zz == 0) ? 2 : (zz == 1) ? 4 : (zz == 2) ? 0 : 6;
    const u16* Bh = Wsp + widx * DD * DD;
    const u16* Bl = Bh + DD * DD;
    const bool split = zz < 2;
    u16* Oh = (zz == 0) ? v2h : a1h;
    u16* Ol = (zz == 0) ? v2l : a1l;
    u16* OT = (zz == 2) ? v1T : a2T;

    __shared__ __align__(16) u16 Ah_s[128 * 32], Al_s[128 * 32];
    __shared__ __align__(16) u16 Bh_s[64 * 32], Bl_s[64 * 32];
    const int m0 = blockIdx.y * 128, n0 = blockIdx.x * 64;
    const int tid = threadIdx.x, lane = tid & 63, w = tid >> 6;
    const int wy = w >> 2, wx = w & 3;
    f32x4 acc[4] = {};

    // A staging: all 512 threads, 1 chunk per tile (row tid>>2, q tid&3)
    const int prow = tid >> 2, pq = tid & 3;
    const int dA = swz(frag_dst(prow, pq * 8));
    const u16* gAh = Ah + (long)(m0 + prow) * DD + pq * 8;
    const u16* gAl = Al + (long)(m0 + prow) * DD + pq * 8;
    // B staging: tid<256 -> Bh, tid>=256 -> Bl (row (tid&255)>>2)
    const int brow = (tid & 255) >> 2, bq = tid & 3;
    const int dB = swz(frag_dst(brow, bq * 8));
    const u16* gB = ((tid < 256) ? Bh : Bl) + (long)(n0 + brow) * DD + bq * 8;
    u16* sB = (tid < 256) ? Bh_s : Bl_s;

    int4 rAh = *(const int4*)(gAh);
    int4 rAl = *(const int4*)(gAl);
    int4 rB  = *(const int4*)(gB);

    for (int k0 = 0; k0 < DD; k0 += 32) {
        *(int4*)(Ah_s + dA) = rAh;
        *(int4*)(Al_s + dA) = rAl;
        *(int4*)(sB + dB)   = rB;
        __syncthreads();
        const int kn = (k0 + 32 < DD) ? k0 + 32 : 0;
        rAh = *(const int4*)(gAh + kn);
        rAl = *(const int4*)(gAl + kn);
        rB  = *(const int4*)(gB + kn);
        short8 ah[4], al[4], bh, bl;
        #pragma unroll
        for (int i = 0; i < 4; ++i) {
            ah[i] = *(const short8*)(Ah_s + swz(((wy * 4 + i) * 64 + lane) * 8));
            al[i] = *(const short8*)(Al_s + swz(((wy * 4 + i) * 64 + lane) * 8));
        }
        bh = *(const short8*)(Bh_s + swz((wx * 64 + lane) * 8));
        bl = *(const short8*)(Bl_s + swz((wx * 64 + lane) * 8));
        #pragma unroll
        for (int i = 0; i < 4; ++i) {
            acc[i] = __builtin_amdgcn_mfma_f32_16x16x32_bf16(ah[i], bl, acc[i], 0, 0, 0);
            acc[i] = __builtin_amdgcn_mfma_f32_16x16x32_bf16(al[i], bh, acc[i], 0, 0, 0);
            acc[i] = __builtin_amdgcn_mfma_f32_16x16x32_bf16(ah[i], bh, acc[i], 0, 0, 0);
        }
        __syncthreads();
    }
    const int quad = lane >> 4, col = lane & 15;
    const int c = n0 + wx * 16 + col;
    #pragma unroll
    for (int i = 0; i < 4; ++i) {
        const int rbase = m0 + wy * 64 + i * 16 + quad * 4;
        if (split) {
            #pragma unroll
            for (int r = 0; r < 4; ++r) {
                const float v = fmaxf(acc[i][r], 0.f);
                const u16 h = f2bf(v);
                Oh[(long)(rbase + r) * DD + c] = h;
                Ol[(long)(rbase + r) * DD + c] = f2bf(v - bf2f(h));
            }
        } else {
            // transposed: OT[b][d=c][t]; 4 consecutive t = one b64 store
            short4 pk;
            pk.x = (short)f2bf(fmaxf(acc[i][0], 0.f));
            pk.y = (short)f2bf(fmaxf(acc[i][1], 0.f));
            pk.z = (short)f2bf(fmaxf(acc[i][2], 0.f));
            pk.w = (short)f2bf(fmaxf(acc[i][3], 0.f));
            const int b = rbase >> 11, t = rbase & (TT - 1);
            *(short4*)(OT + ((long)b * DD + c) * TT + t) = pk;
        }
    }
}

// ---------------------------------------------------------------------------
// Scores: beta(bf16) = relu(v2.a1/16), 3-term split MFMA. BM=BN=128.
// 512 threads = 8 waves (2 wy x 4 wx). Double-buffered LDS (L0/L1, 32KB
// each) + 2-deep register prefetch: ONE barrier per K-step. Step s writes
// L[(s+1)&1] from regs (safe: nobody reads it this step), refills those
// regs 2 steps ahead, reads frags from L[s&1], MFMAs, barriers. The
// barrier drains lgkm, so step-s reads complete before step s+2 rewrites
// that buffer. Numerics identical to R9.
// ---------------------------------------------------------------------------
__global__ __launch_bounds__(512)
void score_kernel(const u16* __restrict__ v2h, const u16* __restrict__ v2l,
                  const u16* __restrict__ a1h, const u16* __restrict__ a1l,
                  u16* __restrict__ beta, u16* __restrict__ betaT,
                  float* __restrict__ rs, float* __restrict__ cs)
{
    // S: two staging buffers (16384 u16 each; per-buffer: Ah 0, Al 4096,
    // Bh 8192, Bl 12288), then reused as the 128x136 epilogue buffer.
    __shared__ __align__(16) u16 S[32768];   // 64 KB
    u16* L0 = S;
    u16* L1 = S + 16384;
    const int z = blockIdx.z;
    const int m0 = blockIdx.y * 128, n0 = blockIdx.x * 128;
    const int tid = threadIdx.x, lane = tid & 63, w = tid >> 6;
    const int wy = w >> 2, wx = w & 3;              // 2 x 4 waves
    const long zoff = (long)z * TT * DD;
    f32x4 acc[4][2] = {};

    // staging: 512 threads, one 16B chunk per tile per thread
    const int prow = tid >> 2, pq = tid & 3;        // row 0..127, k-chunk 0..3
    const int d0 = swz(frag_dst(prow, pq * 8));
    const u16* gAh = v2h + zoff + (long)(m0 + prow) * DD + pq * 8;
    const u16* gAl = v2l + zoff + (long)(m0 + prow) * DD + pq * 8;
    const u16* gBh = a1h + zoff + (long)(n0 + prow) * DD + pq * 8;
    const u16* gBl = a1l + zoff + (long)(n0 + prow) * DD + pq * 8;

    int4 rA0h, rA0l, rB0h, rB0l, rA1h, rA1l, rB1h, rB1l;
    auto refill0 = [&](int k) {
        rA0h = *(const int4*)(gAh + k); rA0l = *(const int4*)(gAl + k);
        rB0h = *(const int4*)(gBh + k); rB0l = *(const int4*)(gBl + k);
    };
    auto refill1 = [&](int k) {
        rA1h = *(const int4*)(gAh + k); rA1l = *(const int4*)(gAl + k);
        rB1h = *(const int4*)(gBh + k); rB1l = *(const int4*)(gBl + k);
    };
    auto stage0 = [&](u16* L) {
        *(int4*)(L + d0) = rA0h;         *(int4*)(L + 4096 + d0) = rA0l;
        *(int4*)(L + 8192 + d0) = rB0h;  *(int4*)(L + 12288 + d0) = rB0l;
    };
    auto stage1 = [&](u16* L) {
        *(int4*)(L + d0) = rA1h;         *(int4*)(L + 4096 + d0) = rA1l;
        *(int4*)(L + 8192 + d0) = rB1h;  *(int4*)(L + 12288 + d0) = rB1l;
    };
    auto compute = [&](const u16* L) {
        short8 ah[4], al[4], bh[2], bl[2];
        #pragma unroll
        for (int i = 0; i < 4; ++i) {
            ah[i] = *(const short8*)(L + swz(((wy * 4 + i) * 64 + lane) * 8));
            al[i] = *(const short8*)(L + 4096 + swz(((wy * 4 + i) * 64 + lane) * 8));
        }
        #pragma unroll
        for (int j = 0; j < 2; ++j) {
            bh[j] = *(const short8*)(L + 8192 + swz(((wx * 2 + j) * 64 + lane) * 8));
            bl[j] = *(const short8*)(L + 12288 + swz(((wx * 2 + j) * 64 + lane) * 8));
        }
        #pragma unroll
        for (int i = 0; i < 4; ++i)
            #pragma unroll
            for (int j = 0; j < 2; ++j) {
                acc[i][j] = __builtin_amdgcn_mfma_f32_16x16x32_bf16(ah[i], bl[j], acc[i][j], 0, 0, 0);
                acc[i][j] = __builtin_amdgcn_mfma_f32_16x16x32_bf16(al[i], bh[j], acc[i][j], 0, 0, 0);
                acc[i][j] = __builtin_amdgcn_mfma_f32_16x16x32_bf16(ah[i], bh[j], acc[i][j], 0, 0, 0);
            }
    };

    // prologue: set0<-k0 staged to L0, set0 refilled k64; set1<-k32
    refill0(0); refill1(32);
    stage0(L0); refill0(64);
    __syncthreads();
    // 8 steps, one barrier each; write next buffer, read current
    stage1(L1); refill1(96);  compute(L0); __syncthreads();   // s0 reads k0
    stage0(L0); refill0(128); compute(L1); __syncthreads();   // s1 reads k32
    stage1(L1); refill1(160); compute(L0); __syncthreads();   // s2 reads k64
    stage0(L0); refill0(192); compute(L1); __syncthreads();   // s3 reads k96
    stage1(L1); refill1(224); compute(L0); __syncthreads();   // s4 reads k128
    stage0(L0);               compute(L1); __syncthreads();   // s5 reads k160
    stage1(L1);               compute(L0); __syncthreads();   // s6 reads k192
                              compute(L1); __syncthreads();   // s7 reads k224

    const int quad = lane >> 4, col = lane & 15;
    const float scale = 1.f / 16.f;
    #pragma unroll
    for (int i = 0; i < 4; ++i)
        #pragma unroll
        for (int j = 0; j < 2; ++j)
            #pragma unroll
            for (int r = 0; r < 4; ++r)
                acc[i][j][r] = fmaxf(acc[i][j][r] * scale, 0.f);

    // beta row-major: stage into S[rl][cl] (stride 136), coalesced int4 out
    #pragma unroll
    for (int i = 0; i < 4; ++i) {
        const int rl = (wy * 4 + i) * 16 + quad * 4;
        #pragma unroll
        for (int j = 0; j < 2; ++j) {
            const int cl = (wx * 2 + j) * 16 + col;
            #pragma unroll
            for (int r = 0; r < 4; ++r)
                S[(rl + r) * 136 + cl] = f2bf(acc[i][j][r]);
        }
    }
    __syncthreads();
    #pragma unroll
    for (int it = 0; it < 4; ++it) {
        const int idx = tid + 512 * it;
        const int rl = idx >> 4, cq = idx & 15;
        const int4 v = *(const int4*)(S + rl * 136 + cq * 8);
        *(int4*)(beta + ((long)z * TT + m0 + rl) * TT + n0 + cq * 8) = v;
    }
    // row sums (fp32-exact atomics): wave partial = its 32 cols
    #pragma unroll
    for (int i = 0; i < 4; ++i)
        #pragma unroll
        for (int r = 0; r < 4; ++r) {
            float rp = acc[i][0][r] + acc[i][1][r];
            rp += __shfl_xor(rp, 1); rp += __shfl_xor(rp, 2);
            rp += __shfl_xor(rp, 4); rp += __shfl_xor(rp, 8);
            if (col == 0) {
                const int row = m0 + (wy * 4 + i) * 16 + quad * 4 + r;
                atomicAdd(&rs[(long)z * TT + row], rp);
            }
        }
    // col sums: wave partial = its 64 rows
    #pragma unroll
    for (int j = 0; j < 2; ++j) {
        float cp = 0.f;
        #pragma unroll
        for (int i = 0; i < 4; ++i)
            #pragma unroll
            for (int r = 0; r < 4; ++r) cp += acc[i][j][r];
        cp += __shfl_xor(cp, 16); cp += __shfl_xor(cp, 32);
        if (lane < 16) {
            const int c = n0 + (wx * 2 + j) * 16 + col;
            atomicAdd(&cs[(long)z * TT + c], cp);
        }
    }
    // betaT via LDS transpose: S[cl][rl] (stride 136), coalesced int4 out
    __syncthreads();
    #pragma unroll
    for (int i = 0; i < 4; ++i)
        #pragma unroll
        for (int j = 0; j < 2; ++j) {
            const int cl = (wx * 2 + j) * 16 + col;
            const int rl = (wy * 4 + i) * 16 + quad * 4;
            short4 pk;
            pk.x = (short)f2bf(acc[i][j][0]);
            pk.y = (short)f2bf(acc[i][j][1]);
            pk.z = (short)f2bf(acc[i][j][2]);
            pk.w = (short)f2bf(acc[i][j][3]);
            *(short4*)(S + cl * 136 + rl) = pk;
        }
    __syncthreads();
    #pragma unroll
    for (int it = 0; it < 4; ++it) {
        const int idx = tid + 512 * it;
        const int cl = idx >> 4, tq = idx & 15;
        const int4 v = *(const int4*)(S + cl * 136 + tq * 8);
        *(int4*)(betaT + ((long)z * TT + n0 + cl) * TT + m0 + tq * 8) = v;
    }
}

// ---------------------------------------------------------------------------
// Unified PV, full-D tile. zz<8: v-attends-a (P=beta, sums=rs, V=a2T,
// resid=v_fea); zz>=8: a-attends-v (P=betaT, sums=cs, V=v1T, resid=a_fea).
// BM=128, BN=256(=D), K=TT. 512 threads = 8 waves (2x4).
// Double-buffered LDS + 2-deep prefetch, ONE barrier per K-step.
// Threshold+rpart happen at stage time, exactly once per chunk
// (prologue k0 + 32 even-step + 31 odd-step chunks = 64).
// ---------------------------------------------------------------------------
__global__ __launch_bounds__(512)
void pv_kernel(const u16* __restrict__ beta, const u16* __restrict__ betaT,
               const u16* __restrict__ a2T, const u16* __restrict__ v1T,
               const float* __restrict__ rs, const float* __restrict__ cs,
               const float* __restrict__ thrp,
               const float* __restrict__ v_fea, const float* __restrict__ a_fea,
               u16* __restrict__ yvin, u16* __restrict__ yain)
{
    // per-buffer: A 4096 u16, B 8192 u16; two buffers
    __shared__ __align__(16) u16 PS[24576];   // 48 KB
    __shared__ float sthr[128], sA[128], ssum[128];
    u16* L0 = PS;
    u16* L1 = PS + 12288;
    const int zz = blockIdx.x;
    const int m0 = blockIdx.y * 128;
    const int z = zz & 7;
    const bool av = zz >= 8;
    const u16* P      = av ? betaT : beta;
    const u16* VT     = av ? v1T : a2T;
    const float* sums = av ? cs : rs;
    const float* resid = av ? a_fea : v_fea;
    u16* outb         = av ? yain : yvin;

    const int tid = threadIdx.x, lane = tid & 63, w = tid >> 6;
    const int wy = w >> 2, wx = w & 3;
    const float thr = thrp[0] * 10.0f / (float)TT;
    if (tid < 128) {
        const float s = sums[(long)z * TT + m0 + tid];
        sA[tid] = s; sthr[tid] = thr * (s + EPSF); ssum[tid] = 0.f;
    }
    __syncthreads();
    f32x4 acc[4][4] = {};
    float rpart = 0.f;
    const int arow = tid >> 2, aq = tid & 3;          // A: 128 rows x 4 chunks
    const u16* Pp = P + ((long)z * TT + m0 + arow) * TT + aq * 8;
    const u16* V0 = VT + (long)z * DD * TT + (long)arow * TT + aq * 8;
    const u16* V1 = V0 + (long)128 * TT;
    const int da  = swz(frag_dst(arow, aq * 8));
    const int db1 = swz(frag_dst(arow + 128, aq * 8));

    int4 A0, B00, B10, A1, B01, B11;
    auto refill0 = [&](int k) {
        A0 = *(const int4*)(Pp + k); B00 = *(const int4*)(V0 + k); B10 = *(const int4*)(V1 + k);
    };
    auto refill1 = [&](int k) {
        A1 = *(const int4*)(Pp + k); B01 = *(const int4*)(V0 + k); B11 = *(const int4*)(V1 + k);
    };
    // threshold A chunk + accumulate rpart + stage into buffer L
    auto stageP = [&](u16* L, const int4& vA, const int4& vB0, const int4& vB1) {
        union { int4 v; u16 us[8]; } U;
        U.v = vA;
        const float cthr = sthr[arow];
        float ss = 0.f;
        #pragma unroll
        for (int t = 0; t < 8; ++t) {
            const float v = bf2f(U.us[t]);
            if (v > cthr) ss += v; else U.us[t] = 0;
        }
        rpart += ss;
        *(int4*)(L + da) = U.v;
        *(int4*)(L + 4096 + da) = vB0;
        *(int4*)(L + 4096 + db1) = vB1;
    };
    auto computeP = [&](const u16* L) {
        short8 a[4], b[4];
        #pragma unroll
        for (int i = 0; i < 4; ++i)
            a[i] = *(const short8*)(L + swz(((wy * 4 + i) * 64 + lane) * 8));
        #pragma unroll
        for (int j = 0; j < 4; ++j)
            b[j] = *(const short8*)(L + 4096 + swz(((wx * 4 + j) * 64 + lane) * 8));
        #pragma unroll
        for (int i = 0; i < 4; ++i)
            #pragma unroll
            for (int j = 0; j < 4; ++j)
                acc[i][j] = __builtin_amdgcn_mfma_f32_16x16x32_bf16(a[i], b[j], acc[i][j], 0, 0, 0);
    };

    // prologue: set0<-k0 staged to L0 (threshold+rpart), refill set0<-k64;
    // set1<-k32
    refill0(0); refill1(32);
    stageP(L0, A0, B00, B10);
    refill0(64);
    __syncthreads();

    for (int k0 = 0; k0 < TT; k0 += 64) {
        // even step: reads L0 (k=k0), writes L1 <- set1 (k=k0+32)
        stageP(L1, A1, B01, B11);
        refill1((k0 + 96 < TT) ? k0 + 96 : 0);     // dead refill never staged
        computeP(L0);
        __syncthreads();
        // odd step: reads L1 (k=k0+32), writes L0 <- set0 (k=k0+64) if valid
        if (k0 + 64 < TT) {
            stageP(L0, A0, B00, B10);
            refill0((k0 + 128 < TT) ? k0 + 128 : 0);
        }
        computeP(L1);
        __syncthreads();
    }
    atomicAdd(&ssum[arow], rpart);
    __syncthreads();

    const int quad = lane >> 4, col = lane & 15;
    #pragma unroll
    for (int i = 0; i < 4; ++i)
        #pragma unroll
        for (int j = 0; j < 4; ++j) {
            const int c = (wx * 4 + j) * 16 + col;
            #pragma unroll
            for (int r = 0; r < 4; ++r) {
                const int lrow = (wy * 4 + i) * 16 + quad * 4 + r;
                const int row = m0 + lrow;
                const float inv = 1.0f / (ssum[lrow] + EPSF * (sA[lrow] + EPSF));
                const float v = acc[i][j][r] * inv + resid[((long)z * TT + row) * DD + c];
                outb[((long)z * TT + row) * DD + c] = f2bf(v);
            }
        }
}

// ---------------------------------------------------------------------------
// FC: y = relu(yin @ Wfc^T), bf16 out. 512 threads = 8 waves (2 wy x 4 wx),
// BM=128, BN=64. z selects branch via fixed strides.
// ---------------------------------------------------------------------------
__global__ __launch_bounds__(512)
void fc_kernel(const u16* __restrict__ Ain, const u16* __restrict__ Wb,
               u16* __restrict__ Cb)
{
    const int z = blockIdx.z;
    const u16* A = Ain + (size_t)z * (size_t)NBATCH * TT * DD;
    const u16* B = Wb + (size_t)z * DD * DD;
    u16* C = Cb + (size_t)z * (size_t)NBATCH * TT * DD;
    __shared__ __align__(16) u16 A_s[128 * 32], B_s[64 * 32];
    const int m0 = blockIdx.y * 128, n0 = blockIdx.x * 64;
    const int tid = threadIdx.x, lane = tid & 63, w = tid >> 6;
    const int wy = w >> 2, wx = w & 3;
    f32x4 acc[4] = {};

    const int prow = tid >> 2, pq = tid & 3;
    const int dA = swz(frag_dst(prow, pq * 8));
    const u16* gA = A + (long)(m0 + prow) * DD + pq * 8;
    const int brow = (tid & 255) >> 2, bq = tid & 3;
    const int dB = swz(frag_dst(brow, bq * 8));
    const u16* gB = B + (long)(n0 + brow) * DD + bq * 8;

    int4 rA = *(const int4*)(gA);
    int4 rB = *(const int4*)(gB);

    for (int k0 = 0; k0 < DD; k0 += 32) {
        *(int4*)(A_s + dA) = rA;
        if (tid < 256) *(int4*)(B_s + dB) = rB;
        __syncthreads();
        const int kn = (k0 + 32 < DD) ? k0 + 32 : 0;
        rA = *(const int4*)(gA + kn);
        rB = *(const int4*)(gB + kn);
        short8 a[4], b;
        #pragma unroll
        for (int i = 0; i < 4; ++i)
            a[i] = *(const short8*)(A_s + swz(((wy * 4 + i) * 64 + lane) * 8));
        b = *(const short8*)(B_s + swz((wx * 64 + lane) * 8));
        #pragma unroll
        for (int i = 0; i < 4; ++i)
            acc[i] = __builtin_amdgcn_mfma_f32_16x16x32_bf16(a[i], b, acc[i], 0, 0, 0);
        __syncthreads();
    }
    const int quad = lane >> 4, col = lane & 15;
    const int c = n0 + wx * 16 + col;
    #pragma unroll
    for (int i = 0; i < 4; ++i) {
        #pragma unroll
        for (int r = 0; r < 4; ++r) {
            const int row = m0 + wy * 64 + i * 16 + quad * 4 + r;
            C[(long)row * DD + c] = f2bf(fmaxf(acc[i][r], 0.f));
        }
    }
}

// ---------------------------------------------------------------------------
// Exact fp32 pred: recompute v2[0,t], a1[0,t] and their dot; compare.
// ---------------------------------------------------------------------------
__global__ __launch_bounds__(256)
void pred_exact(const float* __restrict__ vf, const float* __restrict__ af,
                const float* __restrict__ Wv2, const float* __restrict__ Wa1,
                const float* __restrict__ cs, const float* __restrict__ thrp,
                float* __restrict__ pred)
{
    __shared__ float vs[8][260];
    __shared__ float as_[8][260];
    __shared__ float red[4][8];
    const int t0 = blockIdx.x * 8;
    const int tid = threadIdx.x;
    {
        const int i = tid >> 5, c = (tid & 31) * 8;
        *(float4*)&vs[i][c] = *(const float4*)(vf + (long)(t0 + i) * DD + c);
        *(float4*)&vs[i][c + 4] = *(const float4*)(vf + (long)(t0 + i) * DD + c + 4);
        *(float4*)&as_[i][c] = *(const float4*)(af + (long)(t0 + i) * DD + c);
        *(float4*)&as_[i][c + 4] = *(const float4*)(af + (long)(t0 + i) * DD + c + 4);
    }
    __syncthreads();
    const int j = tid;
    float av[8] = {0.f}, aa[8] = {0.f};
    for (int k = 0; k < DD; k += 4) {
        const float4 wv = *(const float4*)(Wv2 + (long)j * DD + k);
        const float4 wa = *(const float4*)(Wa1 + (long)j * DD + k);
        #pragma unroll
        for (int i = 0; i < 8; ++i) {
            const float4 x = *(const float4*)&vs[i][k];
            av[i] += wv.x * x.x + wv.y * x.y + wv.z * x.z + wv.w * x.w;
            const float4 y = *(const float4*)&as_[i][k];
            aa[i] += wa.x * y.x + wa.y * y.y + wa.z * y.z + wa.w * y.w;
        }
    }
    float p[8];
    #pragma unroll
    for (int i = 0; i < 8; ++i)
        p[i] = fmaxf(av[i], 0.f) * fmaxf(aa[i], 0.f);
    #pragma unroll
    for (int off = 32; off > 0; off >>= 1)
        #pragma unroll
        for (int i = 0; i < 8; ++i) p[i] += __shfl_xor(p[i], off);
    const int lane = tid & 63, wv_ = tid >> 6;
    if (lane == 0)
        #pragma unroll
        for (int i = 0; i < 8; ++i) red[wv_][i] = p[i];
    __syncthreads();
    if (tid < 8) {
        float d = red[0][tid] + red[1][tid] + red[2][tid] + red[3][tid];
        d = fmaxf(d * (1.f / 16.f), 0.f);
        const float thr = thrp[0] * 10.0f / (float)TT;
        pred[t0 + tid] = (d > thr * (cs[t0 + tid] + EPSF)) ? 1.0f : 0.0f;
    }
}

// ---------------------------------------------------------------------------
// Split v_fea/a_fea fp32 -> bf16 h/l pairs. grid.y: 0=v, 1=a.
// ---------------------------------------------------------------------------
__global__ __launch_bounds__(256)
void split_feat(const float* __restrict__ vf, const float* __restrict__ af,
                u16* __restrict__ vfh, u16* __restrict__ vfl,
                u16* __restrict__ afh, u16* __restrict__ afl)
{
    const long i4 = ((long)blockIdx.x * 256 + threadIdx.x) * 4;
    const float* src = blockIdx.y ? af : vf;
    u16* dh = blockIdx.y ? afh : vfh;
    u16* dl = blockIdx.y ? afl : vfl;
    float4 a = *(const float4*)(src + i4);
    ushort4 h4, l4; u16 h;
    h = f2bf(a.x); h4.x = h; l4.x = f2bf(a.x - bf2f(h));
    h = f2bf(a.y); h4.y = h; l4.y = f2bf(a.y - bf2f(h));
    h = f2bf(a.z); h4.z = h; l4.z = f2bf(a.z - bf2f(h));
    h = f2bf(a.w); h4.w = h; l4.w = f2bf(a.w - bf2f(h));
    *(ushort4*)(dh + i4) = h4;
    *(ushort4*)(dl + i4) = l4;
}

// ---------------------------------------------------------------------------
// Split/convert 6 weight matrices into Wsp: [Wv1h Wv1l Wv2h Wv2l Wa1h Wa1l
// Wa2h Wa2l Wvfcb Wafcb], each DD*DD. grid.y = task 0..5.
// ---------------------------------------------------------------------------
__global__ __launch_bounds__(256)
void split_w(const float* __restrict__ w0, const float* __restrict__ w1,
             const float* __restrict__ w2, const float* __restrict__ w3,
             const float* __restrict__ w4, const float* __restrict__ w5,
             u16* __restrict__ out)
{
    const int t = blockIdx.y;
    const float* w = (t == 0) ? w0 : (t == 1) ? w1 : (t == 2) ? w2
                   : (t == 3) ? w3 : (t == 4) ? w4 : w5;
    const int i4 = (blockIdx.x * 256 + threadIdx.x) * 4;
    float4 a = *(const float4*)(w + i4);
    if (t < 4) {
        u16* oh = out + (size_t)t * 2 * DD * DD;
        u16* ol = oh + DD * DD;
        ushort4 h4, l4; u16 h;
        h = f2bf(a.x); h4.x = h; l4.x = f2bf(a.x - bf2f(h));
        h = f2bf(a.y); h4.y = h; l4.y = f2bf(a.y - bf2f(h));
        h = f2bf(a.z); h4.z = h; l4.z = f2bf(a.z - bf2f(h));
        h = f2bf(a.w); h4.w = h; l4.w = f2bf(a.w - bf2f(h));
        *(ushort4*)(oh + i4) = h4;
        *(ushort4*)(ol + i4) = l4;
    } else {
        u16* ob = out + (size_t)8 * DD * DD + (size_t)(t - 4) * DD * DD;
        ushort4 o;
        o.x = f2bf(a.x); o.y = f2bf(a.y); o.z = f2bf(a.z); o.w = f2bf(a.w);
        *(ushort4*)(ob + i4) = o;
    }
}

// ---------------------------------------------------------------------------
// LayerNorm both branches + fuse. 4 rows/block, 1 wave per row. bf16 in,
// fp32 out.
// ---------------------------------------------------------------------------
__global__ __launch_bounds__(256)
void ln_fuse_kernel(const u16* __restrict__ yv, const u16* __restrict__ ya,
                    const float* __restrict__ g, const float* __restrict__ b,
                    float* __restrict__ fuse, float* __restrict__ vpsp,
                    float* __restrict__ apsp)
{
    const long row = (long)blockIdx.x * 4 + (threadIdx.x >> 6);
    const int lane = threadIdx.x & 63;
    const ushort4 hv = *(const ushort4*)(yv + row * DD + lane * 4);
    const ushort4 ha = *(const ushort4*)(ya + row * DD + lane * 4);
    const float xv0 = bf2f(hv.x), xv1 = bf2f(hv.y), xv2 = bf2f(hv.z), xv3 = bf2f(hv.w);
    const float xa0 = bf2f(ha.x), xa1 = bf2f(ha.y), xa2 = bf2f(ha.z), xa3 = bf2f(ha.w);
    float sv = xv0 + xv1 + xv2 + xv3;
    float sa = xa0 + xa1 + xa2 + xa3;
    #pragma unroll
    for (int off = 32; off > 0; off >>= 1) {
        sv += __shfl_xor(sv, off);
        sa += __shfl_xor(sa, off);
    }
    const float mv = sv * (1.f / 256.f);
    const float ma = sa * (1.f / 256.f);
    const float dv0 = xv0 - mv, dv1 = xv1 - mv, dv2 = xv2 - mv, dv3 = xv3 - mv;
    const float da0 = xa0 - ma, da1 = xa1 - ma, da2 = xa2 - ma, da3 = xa3 - ma;
    float qv = dv0 * dv0 + dv1 * dv1 + dv2 * dv2 + dv3 * dv3;
    float qa = da0 * da0 + da1 * da1 + da2 * da2 + da3 * da3;
    #pragma unroll
    for (int off = 32; off > 0; off >>= 1) {
        qv += __shfl_xor(qv, off);
        qa += __shfl_xor(qa, off);
    }
    const float rv = rsqrtf(qv * (1.f / 256.f) + 1e-6f);
    const float ra = rsqrtf(qa * (1.f / 256.f) + 1e-6f);
    const float4 gg = *(const float4*)(g + lane * 4);
    const float4 bb = *(const float4*)(b + lane * 4);
    float4 ov, oa, of;
    ov.x = dv0 * rv * gg.x + bb.x; ov.y = dv1 * rv * gg.y + bb.y;
    ov.z = dv2 * rv * gg.z + bb.z; ov.w = dv3 * rv * gg.w + bb.w;
    oa.x = da0 * ra * gg.x + bb.x; oa.y = da1 * ra * gg.y + bb.y;
    oa.z = da2 * ra * gg.z + bb.z; oa.w = da3 * ra * gg.w + bb.w;
    of.x = 0.5f * (ov.x + oa.x); of.y = 0.5f * (ov.y + oa.y);
    of.z = 0.5f * (ov.z + oa.z); of.w = 0.5f * (ov.w + oa.w);
    *(float4*)(vpsp + row * DD + lane * 4) = ov;
    *(float4*)(apsp + row * DD + lane * 4) = oa;
    *(float4*)(fuse + row * DD + lane * 4) = of;
}

extern "C" void kernel_launch(void* const* d_in, const int* in_sizes, int n_in,
                              void* d_out, int out_size, void* d_ws, size_t ws_size,
                              hipStream_t stream)
{
    const float* a_fea = (const float*)d_in[0];
    const float* v_fea = (const float*)d_in[1];
    const float* thrp  = (const float*)d_in[2];
    const float* Wv1   = (const float*)d_in[3];
    const float* Wv2   = (const float*)d_in[4];
    const float* Wvfc  = (const float*)d_in[5];
    const float* Wa1   = (const float*)d_in[6];
    const float* Wa2   = (const float*)d_in[7];
    const float* Wafc  = (const float*)d_in[8];
    const float* lng   = (const float*)d_in[9];
    const float* lnb   = (const float*)d_in[10];

    const long MT = (long)NBATCH * TT;
    float* out_fuse = (float*)d_out;
    float* out_vpsp = out_fuse + MT * DD;
    float* out_apsp = out_vpsp + MT * DD;
    float* out_pred = out_apsp + MT * DD;

    // ws: v2h v2l a1h a1l yvin yain v1T a2T (8xfb) | rs cs | Wsp(10xDDDD) |
    //     beta(67MB) betaT(67MB). vfh/vfl/afh/afl (transient) alias beta's
    //     front (dead before score writes beta). yvb/yab (fc bf16 out)
    //     alias slots 0-1 (v2h/v2l, dead after score).
    char* ws = (char*)d_ws;
    const size_t fb = (size_t)MT * DD * sizeof(u16);
    const size_t sumB = (size_t)MT * sizeof(float);
    u16* v2h  = (u16*)(ws + 0 * fb);
    u16* v2l  = (u16*)(ws + 1 * fb);
    u16* a1h  = (u16*)(ws + 2 * fb);
    u16* a1l  = (u16*)(ws + 3 * fb);
    u16* yvin = (u16*)(ws + 4 * fb);
    u16* yain = (u16*)(ws + 5 * fb);
    u16* v1T  = (u16*)(ws + 6 * fb);
    u16* a2T  = (u16*)(ws + 7 * fb);
    char* p = ws + 8 * fb;
    float* rs = (float*)(p + 0 * sumB);
    float* cs = (float*)(p + 1 * sumB);
    u16* Wsp  = (u16*)(p + 2 * sumB);
    char* q = p + 2 * sumB + 10 * DD * DD * sizeof(u16);
    const size_t betaB = (size_t)NBATCH * TT * TT * sizeof(u16);   // 67 MB
    u16* beta  = (u16*)q;
    u16* betaT = (u16*)(q + betaB);
    u16* vfh = (u16*)q;            // transient splits, dead before score
    u16* vfl = vfh + MT * DD;
    u16* afh = vfl + MT * DD;
    u16* afl = afh + MT * DD;
    u16* yvb = (u16*)(ws + 0 * fb);        // fc bf16 out, z-stride MT*DD
    u16* yab = yvb + (size_t)MT * DD;

    hipMemsetAsync(rs, 0, 2 * sumB, stream);

    const dim3 blk(256, 1, 1);

    split_feat<<<dim3((unsigned)(MT * DD / 1024), 2, 1), blk, 0, stream>>>(
        v_fea, a_fea, vfh, vfl, afh, afl);
    split_w<<<dim3(DD * DD / 1024, 6, 1), blk, 0, stream>>>(
        Wv1, Wv2, Wa1, Wa2, Wvfc, Wafc, Wsp);

    // 512-thread proj (8 waves), BM=128
    proj_kernel<<<dim3(DD / 64, (unsigned)(MT / 128), 4), dim3(512, 1, 1), 0, stream>>>(
        vfh, vfl, afh, afl, Wsp, v2h, v2l, a1h, a1l, v1T, a2T);

    // 512-thread score (8 waves), dbuf LDS + 2-deep prefetch, 1 barrier/step
    score_kernel<<<dim3(TT / 128, TT / 128, NBATCH), dim3(512, 1, 1), 0, stream>>>(
        v2h, v2l, a1h, a1l, beta, betaT, rs, cs);
    pred_exact<<<dim3(TT / 8, 1, 1), blk, 0, stream>>>(
        v_fea, a_fea, Wv2, Wa1, cs, thrp, out_pred);

    // grid: x = zz (batch+dir, XCD-affine), y = m0 tile; 512 threads
    pv_kernel<<<dim3(2 * NBATCH, TT / 128, 1), dim3(512, 1, 1), 0, stream>>>(
        beta, betaT, a2T, v1T, rs, cs, thrp, v_fea, a_fea, yvin, yain);

    // 512-thread fc (8 waves)
    fc_kernel<<<dim3(DD / 64, (unsigned)(MT / 128), 2), dim3(512, 1, 1), 0, stream>>>(
        yvin, Wsp + 8 * DD * DD, yvb);
    ln_fuse_kernel<<<dim3((unsigned)(MT / 4), 1, 1), blk, 0, stream>>>(
        yvb, yab, lng, lnb, out_fuse, out_vpsp, out_apsp);
}

// Round 11
// 371.239 us; speedup vs baseline: 1.1467x; 1.0005x over previous
//
#include <hip/hip_runtime.h>
#include <math.h>

#define TT 2048
#define DD 256
#define NBATCH 8
#define EPSF 1e-8f

typedef unsigned short u16;
typedef __attribute__((ext_vector_type(8))) short short8;
typedef __attribute__((ext_vector_type(4))) float f32x4;

__device__ __forceinline__ u16 f2bf(float x) {
    unsigned int u = __builtin_bit_cast(unsigned int, x);
    u += 0x7fffu + ((u >> 16) & 1u);
    return (u16)(u >> 16);
}
__device__ __forceinline__ float bf2f(u16 h) {
    return __builtin_bit_cast(float, (unsigned int)h << 16);
}

// MFMA-fragment LDS index for a [rows x 32k] bf16 tile:
// elem(row,k) -> (((row>>4)*4+(k>>3))*16+(row&15))*8+(k&7)
// Fragment read for 16-row subtile t is ds_read_b128 at (t*64+lane)*8.
__device__ __forceinline__ int frag_dst(int row, int k) {
    return (((row >> 4) * 4 + (k >> 3)) * 16 + (row & 15)) * 8 + (k & 7);
}

// Address-pure bank swizzle (u16 index), applied to both write and read.
__device__ __forceinline__ int swz(int i) { return i ^ ((i >> 2) & 32); }

template<int BR>
__device__ __forceinline__ void stage_tile(const u16* __restrict__ g, u16* s,
                                           int row0, int k0, int ldk, int tid)
{
    #pragma unroll
    for (int i = 0; i < BR / 64; ++i) {
        const int c = tid + 256 * i;
        const int row = c >> 2, q = c & 3;
        *(int4*)(s + swz(frag_dst(row, q * 8))) =
            *(const int4*)(g + (long)(row0 + row) * ldk + k0 + q * 8);
    }
}

// ---------------------------------------------------------------------------
// Combined projections. z = 0:v2(split h/l) 1:a1(split h/l)
//                        2:v1 -> v1T (register-transposed bf16)
//                        3:a2 -> a2T
// 3-term split-bf16 MFMA (rel err ~3e-6). 512 threads = 8 waves (2 wy x
// 4 wx), BM=128, BN=64. Outputs bit-identical to the 256-thread version.
// ---------------------------------------------------------------------------
__global__ __launch_bounds__(512)
void proj_kernel(const u16* __restrict__ vfh, const u16* __restrict__ vfl,
                 const u16* __restrict__ afh, const u16* __restrict__ afl,
                 const u16* __restrict__ Wsp,
                 u16* __restrict__ v2h, u16* __restrict__ v2l,
                 u16* __restrict__ a1h, u16* __restrict__ a1l,
                 u16* __restrict__ v1T, u16* __restrict__ a2T)
{
    const int zz = blockIdx.z;
    const u16* Ah = (zz == 1 || zz == 3) ? afh : vfh;
    const u16* Al = (zz == 1 || zz == 3) ? afl : vfl;
    const int widx = (zz == 0) ? 2 : (zz == 1) ? 4 : (zz == 2) ? 0 : 6;
    const u16* Bh = Wsp + widx * DD * DD;
    const u16* Bl = Bh + DD * DD;
    const bool split = zz < 2;
    u16* Oh = (zz == 0) ? v2h : a1h;
    u16* Ol = (zz == 0) ? v2l : a1l;
    u16* OT = (zz == 2) ? v1T : a2T;

    __shared__ __align__(16) u16 Ah_s[128 * 32], Al_s[128 * 32];
    __shared__ __align__(16) u16 Bh_s[64 * 32], Bl_s[64 * 32];
    const int m0 = blockIdx.y * 128, n0 = blockIdx.x * 64;
    const int tid = threadIdx.x, lane = tid & 63, w = tid >> 6;
    const int wy = w >> 2, wx = w & 3;
    f32x4 acc[4] = {};

    // A staging: all 512 threads, 1 chunk per tile (row tid>>2, q tid&3)
    const int prow = tid >> 2, pq = tid & 3;
    const int dA = swz(frag_dst(prow, pq * 8));
    const u16* gAh = Ah + (long)(m0 + prow) * DD + pq * 8;
    const u16* gAl = Al + (long)(m0 + prow) * DD + pq * 8;
    // B staging: tid<256 -> Bh, tid>=256 -> Bl (row (tid&255)>>2)
    const int brow = (tid & 255) >> 2, bq = tid & 3;
    const int dB = swz(frag_dst(brow, bq * 8));
    const u16* gB = ((tid < 256) ? Bh : Bl) + (long)(n0 + brow) * DD + bq * 8;
    u16* sB = (tid < 256) ? Bh_s : Bl_s;

    int4 rAh = *(const int4*)(gAh);
    int4 rAl = *(const int4*)(gAl);
    int4 rB  = *(const int4*)(gB);

    for (int k0 = 0; k0 < DD; k0 += 32) {
        *(int4*)(Ah_s + dA) = rAh;
        *(int4*)(Al_s + dA) = rAl;
        *(int4*)(sB + dB)   = rB;
        __syncthreads();
        const int kn = (k0 + 32 < DD) ? k0 + 32 : 0;
        rAh = *(const int4*)(gAh + kn);
        rAl = *(const int4*)(gAl + kn);
        rB  = *(const int4*)(gB + kn);
        short8 ah[4], al[4], bh, bl;
        #pragma unroll
        for (int i = 0; i < 4; ++i) {
            ah[i] = *(const short8*)(Ah_s + swz(((wy * 4 + i) * 64 + lane) * 8));
            al[i] = *(const short8*)(Al_s + swz(((wy * 4 + i) * 64 + lane) * 8));
        }
        bh = *(const short8*)(Bh_s + swz((wx * 64 + lane) * 8));
        bl = *(const short8*)(Bl_s + swz((wx * 64 + lane) * 8));
        #pragma unroll
        for (int i = 0; i < 4; ++i) {
            acc[i] = __builtin_amdgcn_mfma_f32_16x16x32_bf16(ah[i], bl, acc[i], 0, 0, 0);
            acc[i] = __builtin_amdgcn_mfma_f32_16x16x32_bf16(al[i], bh, acc[i], 0, 0, 0);
            acc[i] = __builtin_amdgcn_mfma_f32_16x16x32_bf16(ah[i], bh, acc[i], 0, 0, 0);
        }
        __syncthreads();
    }
    const int quad = lane >> 4, col = lane & 15;
    const int c = n0 + wx * 16 + col;
    #pragma unroll
    for (int i = 0; i < 4; ++i) {
        const int rbase = m0 + wy * 64 + i * 16 + quad * 4;
        if (split) {
            #pragma unroll
            for (int r = 0; r < 4; ++r) {
                const float v = fmaxf(acc[i][r], 0.f);
                const u16 h = f2bf(v);
                Oh[(long)(rbase + r) * DD + c] = h;
                Ol[(long)(rbase + r) * DD + c] = f2bf(v - bf2f(h));
            }
        } else {
            // transposed: OT[b][d=c][t]; 4 consecutive t = one b64 store
            short4 pk;
            pk.x = (short)f2bf(fmaxf(acc[i][0], 0.f));
            pk.y = (short)f2bf(fmaxf(acc[i][1], 0.f));
            pk.z = (short)f2bf(fmaxf(acc[i][2], 0.f));
            pk.w = (short)f2bf(fmaxf(acc[i][3], 0.f));
            const int b = rbase >> 11, t = rbase & (TT - 1);
            *(short4*)(OT + ((long)b * DD + c) * TT + t) = pk;
        }
    }
}

// ---------------------------------------------------------------------------
// Scores: beta(bf16) = relu(v2.a1/16), 3-term split MFMA. BM=BN=128.
// 512 threads = 8 waves (2 wy x 4 wx). 2-DEEP register-prefetch rotation,
// single LDS buffer set (R9 version -- measured 91us; R10's 64KB dbuf
// regressed to 99.5us: residency loss > barrier savings at 8 K-steps).
// ---------------------------------------------------------------------------
__global__ __launch_bounds__(512)
void score_kernel(const u16* __restrict__ v2h, const u16* __restrict__ v2l,
                  const u16* __restrict__ a1h, const u16* __restrict__ a1l,
                  u16* __restrict__ beta, u16* __restrict__ betaT,
                  float* __restrict__ rs, float* __restrict__ cs)
{
    // S serves as: 4 staging tiles (32 KB) in the K-loop, then the 128x128
    // store buffer (stride 136, 34 KB) in the epilogue.
    __shared__ __align__(16) u16 S[128 * 136];
    u16* Ah_s = S;
    u16* Al_s = S + 4096;
    u16* Bh_s = S + 8192;
    u16* Bl_s = S + 12288;
    const int z = blockIdx.z;
    const int m0 = blockIdx.y * 128, n0 = blockIdx.x * 128;
    const int tid = threadIdx.x, lane = tid & 63, w = tid >> 6;
    const int wy = w >> 2, wx = w & 3;              // 2 x 4 waves
    const long zoff = (long)z * TT * DD;
    f32x4 acc[4][2] = {};

    // staging: 512 threads, one 16B chunk per tile per thread
    const int prow = tid >> 2, pq = tid & 3;        // row 0..127, k-chunk 0..3
    const int d0 = swz(frag_dst(prow, pq * 8));
    const u16* gAh = v2h + zoff + (long)(m0 + prow) * DD + pq * 8;
    const u16* gAl = v2l + zoff + (long)(m0 + prow) * DD + pq * 8;
    const u16* gBh = a1h + zoff + (long)(n0 + prow) * DD + pq * 8;
    const u16* gBl = a1l + zoff + (long)(n0 + prow) * DD + pq * 8;

    // 2-deep prologue: set0 <- k=0, set1 <- k=32
    int4 rA0h = *(const int4*)(gAh),      rA0l = *(const int4*)(gAl);
    int4 rB0h = *(const int4*)(gBh),      rB0l = *(const int4*)(gBl);
    int4 rA1h = *(const int4*)(gAh + 32), rA1l = *(const int4*)(gAl + 32);
    int4 rB1h = *(const int4*)(gBh + 32), rB1l = *(const int4*)(gBl + 32);

    auto kstep = [&](int4& vAh, int4& vAl, int4& vBh, int4& vBl, int kfut) {
        *(int4*)(Ah_s + d0) = vAh;
        *(int4*)(Al_s + d0) = vAl;
        *(int4*)(Bh_s + d0) = vBh;
        *(int4*)(Bl_s + d0) = vBl;
        __syncthreads();
        // refill this set for its next turn (2 steps ahead)
        vAh = *(const int4*)(gAh + kfut);
        vAl = *(const int4*)(gAl + kfut);
        vBh = *(const int4*)(gBh + kfut);
        vBl = *(const int4*)(gBl + kfut);
        short8 ah[4], al[4], bh[2], bl[2];
        #pragma unroll
        for (int i = 0; i < 4; ++i) {
            ah[i] = *(const short8*)(Ah_s + swz(((wy * 4 + i) * 64 + lane) * 8));
            al[i] = *(const short8*)(Al_s + swz(((wy * 4 + i) * 64 + lane) * 8));
        }
        #pragma unroll
        for (int j = 0; j < 2; ++j) {
            bh[j] = *(const short8*)(Bh_s + swz(((wx * 2 + j) * 64 + lane) * 8));
            bl[j] = *(const short8*)(Bl_s + swz(((wx * 2 + j) * 64 + lane) * 8));
        }
        #pragma unroll
        for (int i = 0; i < 4; ++i)
            #pragma unroll
            for (int j = 0; j < 2; ++j) {
                acc[i][j] = __builtin_amdgcn_mfma_f32_16x16x32_bf16(ah[i], bl[j], acc[i][j], 0, 0, 0);
                acc[i][j] = __builtin_amdgcn_mfma_f32_16x16x32_bf16(al[i], bh[j], acc[i][j], 0, 0, 0);
                acc[i][j] = __builtin_amdgcn_mfma_f32_16x16x32_bf16(ah[i], bh[j], acc[i][j], 0, 0, 0);
            }
        __syncthreads();
    };
    // 8 K-steps, fully unrolled; dead refills (past K) reload k=0 harmlessly
    kstep(rA0h, rA0l, rB0h, rB0l, 64);
    kstep(rA1h, rA1l, rB1h, rB1l, 96);
    kstep(rA0h, rA0l, rB0h, rB0l, 128);
    kstep(rA1h, rA1l, rB1h, rB1l, 160);
    kstep(rA0h, rA0l, rB0h, rB0l, 192);
    kstep(rA1h, rA1l, rB1h, rB1l, 224);
    kstep(rA0h, rA0l, rB0h, rB0l, 0);
    kstep(rA1h, rA1l, rB1h, rB1l, 0);

    const int quad = lane >> 4, col = lane & 15;
    const float scale = 1.f / 16.f;
    #pragma unroll
    for (int i = 0; i < 4; ++i)
        #pragma unroll
        for (int j = 0; j < 2; ++j)
            #pragma unroll
            for (int r = 0; r < 4; ++r)
                acc[i][j][r] = fmaxf(acc[i][j][r] * scale, 0.f);

    // beta row-major: stage into S[rl][cl] (stride 136), coalesced int4 out
    #pragma unroll
    for (int i = 0; i < 4; ++i) {
        const int rl = (wy * 4 + i) * 16 + quad * 4;
        #pragma unroll
        for (int j = 0; j < 2; ++j) {
            const int cl = (wx * 2 + j) * 16 + col;
            #pragma unroll
            for (int r = 0; r < 4; ++r)
                S[(rl + r) * 136 + cl] = f2bf(acc[i][j][r]);
        }
    }
    __syncthreads();
    #pragma unroll
    for (int it = 0; it < 4; ++it) {
        const int idx = tid + 512 * it;
        const int rl = idx >> 4, cq = idx & 15;
        const int4 v = *(const int4*)(S + rl * 136 + cq * 8);
        *(int4*)(beta + ((long)z * TT + m0 + rl) * TT + n0 + cq * 8) = v;
    }
    // row sums (fp32-exact atomics): wave partial = its 32 cols
    #pragma unroll
    for (int i = 0; i < 4; ++i)
        #pragma unroll
        for (int r = 0; r < 4; ++r) {
            float rp = acc[i][0][r] + acc[i][1][r];
            rp += __shfl_xor(rp, 1); rp += __shfl_xor(rp, 2);
            rp += __shfl_xor(rp, 4); rp += __shfl_xor(rp, 8);
            if (col == 0) {
                const int row = m0 + (wy * 4 + i) * 16 + quad * 4 + r;
                atomicAdd(&rs[(long)z * TT + row], rp);
            }
        }
    // col sums: wave partial = its 64 rows
    #pragma unroll
    for (int j = 0; j < 2; ++j) {
        float cp = 0.f;
        #pragma unroll
        for (int i = 0; i < 4; ++i)
            #pragma unroll
            for (int r = 0; r < 4; ++r) cp += acc[i][j][r];
        cp += __shfl_xor(cp, 16); cp += __shfl_xor(cp, 32);
        if (lane < 16) {
            const int c = n0 + (wx * 2 + j) * 16 + col;
            atomicAdd(&cs[(long)z * TT + c], cp);
        }
    }
    // betaT via LDS transpose: S[cl][rl] (stride 136), coalesced int4 out
    __syncthreads();
    #pragma unroll
    for (int i = 0; i < 4; ++i)
        #pragma unroll
        for (int j = 0; j < 2; ++j) {
            const int cl = (wx * 2 + j) * 16 + col;
            const int rl = (wy * 4 + i) * 16 + quad * 4;
            short4 pk;
            pk.x = (short)f2bf(acc[i][j][0]);
            pk.y = (short)f2bf(acc[i][j][1]);
            pk.z = (short)f2bf(acc[i][j][2]);
            pk.w = (short)f2bf(acc[i][j][3]);
            *(short4*)(S + cl * 136 + rl) = pk;
        }
    __syncthreads();
    #pragma unroll
    for (int it = 0; it < 4; ++it) {
        const int idx = tid + 512 * it;
        const int cl = idx >> 4, tq = idx & 15;
        const int4 v = *(const int4*)(S + cl * 136 + tq * 8);
        *(int4*)(betaT + ((long)z * TT + n0 + cl) * TT + m0 + tq * 8) = v;
    }
}

// ---------------------------------------------------------------------------
// Unified PV, full-D tile. zz<8: v-attends-a (P=beta, sums=rs, V=a2T,
// resid=v_fea); zz>=8: a-attends-v (P=betaT, sums=cs, V=v1T, resid=a_fea).
// BM=128, BN=256(=D), K=TT. 512 threads = 8 waves (2x4).
// Double-buffered LDS + 2-deep prefetch, ONE barrier per K-step (R10
// version -- measured winner for the 64-step loop; 1 block/CU regardless).
// ---------------------------------------------------------------------------
__global__ __launch_bounds__(512)
void pv_kernel(const u16* __restrict__ beta, const u16* __restrict__ betaT,
               const u16* __restrict__ a2T, const u16* __restrict__ v1T,
               const float* __restrict__ rs, const float* __restrict__ cs,
               const float* __restrict__ thrp,
               const float* __restrict__ v_fea, const float* __restrict__ a_fea,
               u16* __restrict__ yvin, u16* __restrict__ yain)
{
    // per-buffer: A 4096 u16, B 8192 u16; two buffers
    __shared__ __align__(16) u16 PS[24576];   // 48 KB
    __shared__ float sthr[128], sA[128], ssum[128];
    u16* L0 = PS;
    u16* L1 = PS + 12288;
    const int zz = blockIdx.x;
    const int m0 = blockIdx.y * 128;
    const int z = zz & 7;
    const bool av = zz >= 8;
    const u16* P      = av ? betaT : beta;
    const u16* VT     = av ? v1T : a2T;
    const float* sums = av ? cs : rs;
    const float* resid = av ? a_fea : v_fea;
    u16* outb         = av ? yain : yvin;

    const int tid = threadIdx.x, lane = tid & 63, w = tid >> 6;
    const int wy = w >> 2, wx = w & 3;
    const float thr = thrp[0] * 10.0f / (float)TT;
    if (tid < 128) {
        const float s = sums[(long)z * TT + m0 + tid];
        sA[tid] = s; sthr[tid] = thr * (s + EPSF); ssum[tid] = 0.f;
    }
    __syncthreads();
    f32x4 acc[4][4] = {};
    float rpart = 0.f;
    const int arow = tid >> 2, aq = tid & 3;          // A: 128 rows x 4 chunks
    const u16* Pp = P + ((long)z * TT + m0 + arow) * TT + aq * 8;
    const u16* V0 = VT + (long)z * DD * TT + (long)arow * TT + aq * 8;
    const u16* V1 = V0 + (long)128 * TT;
    const int da  = swz(frag_dst(arow, aq * 8));
    const int db1 = swz(frag_dst(arow + 128, aq * 8));

    int4 A0, B00, B10, A1, B01, B11;
    auto refill0 = [&](int k) {
        A0 = *(const int4*)(Pp + k); B00 = *(const int4*)(V0 + k); B10 = *(const int4*)(V1 + k);
    };
    auto refill1 = [&](int k) {
        A1 = *(const int4*)(Pp + k); B01 = *(const int4*)(V0 + k); B11 = *(const int4*)(V1 + k);
    };
    // threshold A chunk + accumulate rpart + stage into buffer L
    auto stageP = [&](u16* L, const int4& vA, const int4& vB0, const int4& vB1) {
        union { int4 v; u16 us[8]; } U;
        U.v = vA;
        const float cthr = sthr[arow];
        float ss = 0.f;
        #pragma unroll
        for (int t = 0; t < 8; ++t) {
            const float v = bf2f(U.us[t]);
            if (v > cthr) ss += v; else U.us[t] = 0;
        }
        rpart += ss;
        *(int4*)(L + da) = U.v;
        *(int4*)(L + 4096 + da) = vB0;
        *(int4*)(L + 4096 + db1) = vB1;
    };
    auto computeP = [&](const u16* L) {
        short8 a[4], b[4];
        #pragma unroll
        for (int i = 0; i < 4; ++i)
            a[i] = *(const short8*)(L + swz(((wy * 4 + i) * 64 + lane) * 8));
        #pragma unroll
        for (int j = 0; j < 4; ++j)
            b[j] = *(const short8*)(L + 4096 + swz(((wx * 4 + j) * 64 + lane) * 8));
        #pragma unroll
        for (int i = 0; i < 4; ++i)
            #pragma unroll
            for (int j = 0; j < 4; ++j)
                acc[i][j] = __builtin_amdgcn_mfma_f32_16x16x32_bf16(a[i], b[j], acc[i][j], 0, 0, 0);
    };

    // prologue: set0<-k0 staged to L0 (threshold+rpart), refill set0<-k64;
    // set1<-k32
    refill0(0); refill1(32);
    stageP(L0, A0, B00, B10);
    refill0(64);
    __syncthreads();

    for (int k0 = 0; k0 < TT; k0 += 64) {
        // even step: reads L0 (k=k0), writes L1 <- set1 (k=k0+32)
        stageP(L1, A1, B01, B11);
        refill1((k0 + 96 < TT) ? k0 + 96 : 0);     // dead refill never staged
        computeP(L0);
        __syncthreads();
        // odd step: reads L1 (k=k0+32), writes L0 <- set0 (k=k0+64) if valid
        if (k0 + 64 < TT) {
            stageP(L0, A0, B00, B10);
            refill0((k0 + 128 < TT) ? k0 + 128 : 0);
        }
        computeP(L1);
        __syncthreads();
    }
    atomicAdd(&ssum[arow], rpart);
    __syncthreads();

    const int quad = lane >> 4, col = lane & 15;
    #pragma unroll
    for (int i = 0; i < 4; ++i)
        #pragma unroll
        for (int j = 0; j < 4; ++j) {
            const int c = (wx * 4 + j) * 16 + col;
            #pragma unroll
            for (int r = 0; r < 4; ++r) {
                const int lrow = (wy * 4 + i) * 16 + quad * 4 + r;
                const int row = m0 + lrow;
                const float inv = 1.0f / (ssum[lrow] + EPSF * (sA[lrow] + EPSF));
                const float v = acc[i][j][r] * inv + resid[((long)z * TT + row) * DD + c];
                outb[((long)z * TT + row) * DD + c] = f2bf(v);
            }
        }
}

// ---------------------------------------------------------------------------
// FC: y = relu(yin @ Wfc^T), bf16 out. 512 threads = 8 waves (2 wy x 4 wx),
// BM=128, BN=64. z selects branch via fixed strides.
// ---------------------------------------------------------------------------
__global__ __launch_bounds__(512)
void fc_kernel(const u16* __restrict__ Ain, const u16* __restrict__ Wb,
               u16* __restrict__ Cb)
{
    const int z = blockIdx.z;
    const u16* A = Ain + (size_t)z * (size_t)NBATCH * TT * DD;
    const u16* B = Wb + (size_t)z * DD * DD;
    u16* C = Cb + (size_t)z * (size_t)NBATCH * TT * DD;
    __shared__ __align__(16) u16 A_s[128 * 32], B_s[64 * 32];
    const int m0 = blockIdx.y * 128, n0 = blockIdx.x * 64;
    const int tid = threadIdx.x, lane = tid & 63, w = tid >> 6;
    const int wy = w >> 2, wx = w & 3;
    f32x4 acc[4] = {};

    const int prow = tid >> 2, pq = tid & 3;
    const int dA = swz(frag_dst(prow, pq * 8));
    const u16* gA = A + (long)(m0 + prow) * DD + pq * 8;
    const int brow = (tid & 255) >> 2, bq = tid & 3;
    const int dB = swz(frag_dst(brow, bq * 8));
    const u16* gB = B + (long)(n0 + brow) * DD + bq * 8;

    int4 rA = *(const int4*)(gA);
    int4 rB = *(const int4*)(gB);

    for (int k0 = 0; k0 < DD; k0 += 32) {
        *(int4*)(A_s + dA) = rA;
        if (tid < 256) *(int4*)(B_s + dB) = rB;
        __syncthreads();
        const int kn = (k0 + 32 < DD) ? k0 + 32 : 0;
        rA = *(const int4*)(gA + kn);
        rB = *(const int4*)(gB + kn);
        short8 a[4], b;
        #pragma unroll
        for (int i = 0; i < 4; ++i)
            a[i] = *(const short8*)(A_s + swz(((wy * 4 + i) * 64 + lane) * 8));
        b = *(const short8*)(B_s + swz((wx * 64 + lane) * 8));
        #pragma unroll
        for (int i = 0; i < 4; ++i)
            acc[i] = __builtin_amdgcn_mfma_f32_16x16x32_bf16(a[i], b, acc[i], 0, 0, 0);
        __syncthreads();
    }
    const int quad = lane >> 4, col = lane & 15;
    const int c = n0 + wx * 16 + col;
    #pragma unroll
    for (int i = 0; i < 4; ++i) {
        #pragma unroll
        for (int r = 0; r < 4; ++r) {
            const int row = m0 + wy * 64 + i * 16 + quad * 4 + r;
            C[(long)row * DD + c] = f2bf(fmaxf(acc[i][r], 0.f));
        }
    }
}

// ---------------------------------------------------------------------------
// Exact fp32 pred: recompute v2[0,t], a1[0,t] and their dot; compare.
// ---------------------------------------------------------------------------
__global__ __launch_bounds__(256)
void pred_exact(const float* __restrict__ vf, const float* __restrict__ af,
                const float* __restrict__ Wv2, const float* __restrict__ Wa1,
                const float* __restrict__ cs, const float* __restrict__ thrp,
                float* __restrict__ pred)
{
    __shared__ float vs[8][260];
    __shared__ float as_[8][260];
    __shared__ float red[4][8];
    const int t0 = blockIdx.x * 8;
    const int tid = threadIdx.x;
    {
        const int i = tid >> 5, c = (tid & 31) * 8;
        *(float4*)&vs[i][c] = *(const float4*)(vf + (long)(t0 + i) * DD + c);
        *(float4*)&vs[i][c + 4] = *(const float4*)(vf + (long)(t0 + i) * DD + c + 4);
        *(float4*)&as_[i][c] = *(const float4*)(af + (long)(t0 + i) * DD + c);
        *(float4*)&as_[i][c + 4] = *(const float4*)(af + (long)(t0 + i) * DD + c + 4);
    }
    __syncthreads();
    const int j = tid;
    float av[8] = {0.f}, aa[8] = {0.f};
    for (int k = 0; k < DD; k += 4) {
        const float4 wv = *(const float4*)(Wv2 + (long)j * DD + k);
        const float4 wa = *(const float4*)(Wa1 + (long)j * DD + k);
        #pragma unroll
        for (int i = 0; i < 8; ++i) {
            const float4 x = *(const float4*)&vs[i][k];
            av[i] += wv.x * x.x + wv.y * x.y + wv.z * x.z + wv.w * x.w;
            const float4 y = *(const float4*)&as_[i][k];
            aa[i] += wa.x * y.x + wa.y * y.y + wa.z * y.z + wa.w * y.w;
        }
    }
    float p[8];
    #pragma unroll
    for (int i = 0; i < 8; ++i)
        p[i] = fmaxf(av[i], 0.f) * fmaxf(aa[i], 0.f);
    #pragma unroll
    for (int off = 32; off > 0; off >>= 1)
        #pragma unroll
        for (int i = 0; i < 8; ++i) p[i] += __shfl_xor(p[i], off);
    const int lane = tid & 63, wv_ = tid >> 6;
    if (lane == 0)
        #pragma unroll
        for (int i = 0; i < 8; ++i) red[wv_][i] = p[i];
    __syncthreads();
    if (tid < 8) {
        float d = red[0][tid] + red[1][tid] + red[2][tid] + red[3][tid];
        d = fmaxf(d * (1.f / 16.f), 0.f);
        const float thr = thrp[0] * 10.0f / (float)TT;
        pred[t0 + tid] = (d > thr * (cs[t0 + tid] + EPSF)) ? 1.0f : 0.0f;
    }
}

// ---------------------------------------------------------------------------
// Split v_fea/a_fea fp32 -> bf16 h/l pairs. grid.y: 0=v, 1=a.
// ---------------------------------------------------------------------------
__global__ __launch_bounds__(256)
void split_feat(const float* __restrict__ vf, const float* __restrict__ af,
                u16* __restrict__ vfh, u16* __restrict__ vfl,
                u16* __restrict__ afh, u16* __restrict__ afl)
{
    const long i4 = ((long)blockIdx.x * 256 + threadIdx.x) * 4;
    const float* src = blockIdx.y ? af : vf;
    u16* dh = blockIdx.y ? afh : vfh;
    u16* dl = blockIdx.y ? afl : vfl;
    float4 a = *(const float4*)(src + i4);
    ushort4 h4, l4; u16 h;
    h = f2bf(a.x); h4.x = h; l4.x = f2bf(a.x - bf2f(h));
    h = f2bf(a.y); h4.y = h; l4.y = f2bf(a.y - bf2f(h));
    h = f2bf(a.z); h4.z = h; l4.z = f2bf(a.z - bf2f(h));
    h = f2bf(a.w); h4.w = h; l4.w = f2bf(a.w - bf2f(h));
    *(ushort4*)(dh + i4) = h4;
    *(ushort4*)(dl + i4) = l4;
}

// ---------------------------------------------------------------------------
// Split/convert 6 weight matrices into Wsp: [Wv1h Wv1l Wv2h Wv2l Wa1h Wa1l
// Wa2h Wa2l Wvfcb Wafcb], each DD*DD. grid.y = task 0..5.
// ---------------------------------------------------------------------------
__global__ __launch_bounds__(256)
void split_w(const float* __restrict__ w0, const float* __restrict__ w1,
             const float* __restrict__ w2, const float* __restrict__ w3,
             const float* __restrict__ w4, const float* __restrict__ w5,
             u16* __restrict__ out)
{
    const int t = blockIdx.y;
    const float* w = (t == 0) ? w0 : (t == 1) ? w1 : (t == 2) ? w2
                   : (t == 3) ? w3 : (t == 4) ? w4 : w5;
    const int i4 = (blockIdx.x * 256 + threadIdx.x) * 4;
    float4 a = *(const float4*)(w + i4);
    if (t < 4) {
        u16* oh = out + (size_t)t * 2 * DD * DD;
        u16* ol = oh + DD * DD;
        ushort4 h4, l4; u16 h;
        h = f2bf(a.x); h4.x = h; l4.x = f2bf(a.x - bf2f(h));
        h = f2bf(a.y); h4.y = h; l4.y = f2bf(a.y - bf2f(h));
        h = f2bf(a.z); h4.z = h; l4.z = f2bf(a.z - bf2f(h));
        h = f2bf(a.w); h4.w = h; l4.w = f2bf(a.w - bf2f(h));
        *(ushort4*)(oh + i4) = h4;
        *(ushort4*)(ol + i4) = l4;
    } else {
        u16* ob = out + (size_t)8 * DD * DD + (size_t)(t - 4) * DD * DD;
        ushort4 o;
        o.x = f2bf(a.x); o.y = f2bf(a.y); o.z = f2bf(a.z); o.w = f2bf(a.w);
        *(ushort4*)(ob + i4) = o;
    }
}

// ---------------------------------------------------------------------------
// LayerNorm both branches + fuse. 4 rows/block, 1 wave per row. bf16 in,
// fp32 out.
// ---------------------------------------------------------------------------
__global__ __launch_bounds__(256)
void ln_fuse_kernel(const u16* __restrict__ yv, const u16* __restrict__ ya,
                    const float* __restrict__ g, const float* __restrict__ b,
                    float* __restrict__ fuse, float* __restrict__ vpsp,
                    float* __restrict__ apsp)
{
    const long row = (long)blockIdx.x * 4 + (threadIdx.x >> 6);
    const int lane = threadIdx.x & 63;
    const ushort4 hv = *(const ushort4*)(yv + row * DD + lane * 4);
    const ushort4 ha = *(const ushort4*)(ya + row * DD + lane * 4);
    const float xv0 = bf2f(hv.x), xv1 = bf2f(hv.y), xv2 = bf2f(hv.z), xv3 = bf2f(hv.w);
    const float xa0 = bf2f(ha.x), xa1 = bf2f(ha.y), xa2 = bf2f(ha.z), xa3 = bf2f(ha.w);
    float sv = xv0 + xv1 + xv2 + xv3;
    float sa = xa0 + xa1 + xa2 + xa3;
    #pragma unroll
    for (int off = 32; off > 0; off >>= 1) {
        sv += __shfl_xor(sv, off);
        sa += __shfl_xor(sa, off);
    }
    const float mv = sv * (1.f / 256.f);
    const float ma = sa * (1.f / 256.f);
    const float dv0 = xv0 - mv, dv1 = xv1 - mv, dv2 = xv2 - mv, dv3 = xv3 - mv;
    const float da0 = xa0 - ma, da1 = xa1 - ma, da2 = xa2 - ma, da3 = xa3 - ma;
    float qv = dv0 * dv0 + dv1 * dv1 + dv2 * dv2 + dv3 * dv3;
    float qa = da0 * da0 + da1 * da1 + da2 * da2 + da3 * da3;
    #pragma unroll
    for (int off = 32; off > 0; off >>= 1) {
        qv += __shfl_xor(qv, off);
        qa += __shfl_xor(qa, off);
    }
    const float rv = rsqrtf(qv * (1.f / 256.f) + 1e-6f);
    const float ra = rsqrtf(qa * (1.f / 256.f) + 1e-6f);
    const float4 gg = *(const float4*)(g + lane * 4);
    const float4 bb = *(const float4*)(b + lane * 4);
    float4 ov, oa, of;
    ov.x = dv0 * rv * gg.x + bb.x; ov.y = dv1 * rv * gg.y + bb.y;
    ov.z = dv2 * rv * gg.z + bb.z; ov.w = dv3 * rv * gg.w + bb.w;
    oa.x = da0 * ra * gg.x + bb.x; oa.y = da1 * ra * gg.y + bb.y;
    oa.z = da2 * ra * gg.z + bb.z; oa.w = da3 * ra * gg.w + bb.w;
    of.x = 0.5f * (ov.x + oa.x); of.y = 0.5f * (ov.y + oa.y);
    of.z = 0.5f * (ov.z + oa.z); of.w = 0.5f * (ov.w + oa.w);
    *(float4*)(vpsp + row * DD + lane * 4) = ov;
    *(float4*)(apsp + row * DD + lane * 4) = oa;
    *(float4*)(fuse + row * DD + lane * 4) = of;
}

extern "C" void kernel_launch(void* const* d_in, const int* in_sizes, int n_in,
                              void* d_out, int out_size, void* d_ws, size_t ws_size,
                              hipStream_t stream)
{
    const float* a_fea = (const float*)d_in[0];
    const float* v_fea = (const float*)d_in[1];
    const float* thrp  = (const float*)d_in[2];
    const float* Wv1   = (const float*)d_in[3];
    const float* Wv2   = (const float*)d_in[4];
    const float* Wvfc  = (const float*)d_in[5];
    const float* Wa1   = (const float*)d_in[6];
    const float* Wa2   = (const float*)d_in[7];
    const float* Wafc  = (const float*)d_in[8];
    const float* lng   = (const float*)d_in[9];
    const float* lnb   = (const float*)d_in[10];

    const long MT = (long)NBATCH * TT;
    float* out_fuse = (float*)d_out;
    float* out_vpsp = out_fuse + MT * DD;
    float* out_apsp = out_vpsp + MT * DD;
    float* out_pred = out_apsp + MT * DD;

    // ws: v2h v2l a1h a1l yvin yain v1T a2T (8xfb) | rs cs | Wsp(10xDDDD) |
    //     beta(67MB) betaT(67MB). vfh/vfl/afh/afl (transient) alias beta's
    //     front (dead before score writes beta). yvb/yab (fc bf16 out)
    //     alias slots 0-1 (v2h/v2l, dead after score).
    char* ws = (char*)d_ws;
    const size_t fb = (size_t)MT * DD * sizeof(u16);
    const size_t sumB = (size_t)MT * sizeof(float);
    u16* v2h  = (u16*)(ws + 0 * fb);
    u16* v2l  = (u16*)(ws + 1 * fb);
    u16* a1h  = (u16*)(ws + 2 * fb);
    u16* a1l  = (u16*)(ws + 3 * fb);
    u16* yvin = (u16*)(ws + 4 * fb);
    u16* yain = (u16*)(ws + 5 * fb);
    u16* v1T  = (u16*)(ws + 6 * fb);
    u16* a2T  = (u16*)(ws + 7 * fb);
    char* p = ws + 8 * fb;
    float* rs = (float*)(p + 0 * sumB);
    float* cs = (float*)(p + 1 * sumB);
    u16* Wsp  = (u16*)(p + 2 * sumB);
    char* q = p + 2 * sumB + 10 * DD * DD * sizeof(u16);
    const size_t betaB = (size_t)NBATCH * TT * TT * sizeof(u16);   // 67 MB
    u16* beta  = (u16*)q;
    u16* betaT = (u16*)(q + betaB);
    u16* vfh = (u16*)q;            // transient splits, dead before score
    u16* vfl = vfh + MT * DD;
    u16* afh = vfl + MT * DD;
    u16* afl = afh + MT * DD;
    u16* yvb = (u16*)(ws + 0 * fb);        // fc bf16 out, z-stride MT*DD
    u16* yab = yvb + (size_t)MT * DD;

    hipMemsetAsync(rs, 0, 2 * sumB, stream);

    const dim3 blk(256, 1, 1);

    split_feat<<<dim3((unsigned)(MT * DD / 1024), 2, 1), blk, 0, stream>>>(
        v_fea, a_fea, vfh, vfl, afh, afl);
    split_w<<<dim3(DD * DD / 1024, 6, 1), blk, 0, stream>>>(
        Wv1, Wv2, Wa1, Wa2, Wvfc, Wafc, Wsp);

    // 512-thread proj (8 waves), BM=128
    proj_kernel<<<dim3(DD / 64, (unsigned)(MT / 128), 4), dim3(512, 1, 1), 0, stream>>>(
        vfh, vfl, afh, afl, Wsp, v2h, v2l, a1h, a1l, v1T, a2T);

    // 512-thread score (8 waves), R9 single-buffer 2-deep prefetch
    score_kernel<<<dim3(TT / 128, TT / 128, NBATCH), dim3(512, 1, 1), 0, stream>>>(
        v2h, v2l, a1h, a1l, beta, betaT, rs, cs);
    pred_exact<<<dim3(TT / 8, 1, 1), blk, 0, stream>>>(
        v_fea, a_fea, Wv2, Wa1, cs, thrp, out_pred);

    // grid: x = zz (batch+dir, XCD-affine), y = m0 tile; 512 threads
    pv_kernel<<<dim3(2 * NBATCH, TT / 128, 1), dim3(512, 1, 1), 0, stream>>>(
        beta, betaT, a2T, v1T, rs, cs, thrp, v_fea, a_fea, yvin, yain);

    // 512-thread fc (8 waves)
    fc_kernel<<<dim3(DD / 64, (unsigned)(MT / 128), 2), dim3(512, 1, 1), 0, stream>>>(
        yvin, Wsp + 8 * DD * DD, yvb);
    ln_fuse_kernel<<<dim3((unsigned)(MT / 4), 1, 1), blk, 0, stream>>>(
        yvb, yab, lng, lnb, out_fuse, out_vpsp, out_apsp);
}